// Round 6
// baseline (1631.602 us; speedup 1.0000x reference)
//
#include <hip/hip_runtime.h>
#include <math.h>

#define Bb    32
#define Nn    4096
#define HISTC 16
#define PREDC 8
#define TTC   24
#define EC    65536
#define BN    (Bb*Nn)          // 131072

typedef float f32x2 __attribute__((ext_vector_type(2)));

__device__ __forceinline__ float sigm_f(float x){
  return __builtin_amdgcn_rcpf(1.f + __expf(-x));
}
__device__ __forceinline__ float tanh_f(float x){
  return fmaf(-2.f, __builtin_amdgcn_rcpf(1.f + __expf(2.f*x)), 1.f);
}
__device__ __forceinline__ f32x2 sig2(f32x2 a){ f32x2 r; r.x=sigm_f(a.x); r.y=sigm_f(a.y); return r; }
__device__ __forceinline__ f32x2 th2 (f32x2 a){ f32x2 r; r.x=tanh_f(a.x); r.y=tanh_f(a.y); return r; }

// ---------------- CSR build ----------------
__global__ void k_deg(const int* __restrict__ ei, int* deg, int* cnt){
  int e = blockIdx.x*blockDim.x + threadIdx.x;
  if (e < EC){ atomicAdd(&deg[ei[e]],1); atomicAdd(&cnt[ei[EC+e]],1); }
}
__global__ void k_dis(const int* __restrict__ deg, float* dis){
  int n = blockIdx.x*blockDim.x + threadIdx.x;
  if (n < Nn) dis[n] = deg[n] > 0 ? rsqrtf((float)deg[n]) : 0.f;
}
__global__ void k_scan(const int* __restrict__ cnt, int* ptr){
  __shared__ int sd[1024];
  int t = threadIdx.x;
  int c0=cnt[4*t], c1=cnt[4*t+1], c2=cnt[4*t+2], c3=cnt[4*t+3];
  int s = c0+c1+c2+c3;
  sd[t] = s; __syncthreads();
  for (int off=1; off<1024; off<<=1){
    int v = (t>=off) ? sd[t-off] : 0;
    __syncthreads();
    sd[t] += v;
    __syncthreads();
  }
  int excl = sd[t]-s;
  ptr[4*t]=excl; ptr[4*t+1]=excl+c0; ptr[4*t+2]=excl+c0+c1; ptr[4*t+3]=excl+c0+c1+c2;
  if (t==1023) ptr[4096]=sd[1023];
}
// edges packed: (src, bits(norm)) one 8B load per edge
__global__ void k_fill(const int* __restrict__ ei, const float* __restrict__ dis,
                       const int* __restrict__ ptr, int* fillc, int2* __restrict__ epack){
  int e = blockIdx.x*blockDim.x + threadIdx.x;
  if (e < EC){
    int s = ei[e], d = ei[EC+e];
    int pos = ptr[d] + atomicAdd(&fillc[d],1);
    epack[pos] = make_int2(s, __float_as_int(-dis[s]*dis[d]));
  }
}
// concat weights [44][128] f32 (x2h rows then h2h rows); bias sum
__global__ void k_prep(const float* __restrict__ x2hw, const float* __restrict__ h2hw,
                       const float* __restrict__ x2hb, const float* __restrict__ h2hb,
                       float* __restrict__ wcat, float* __restrict__ bsum){
  int i = blockIdx.x*256 + threadIdx.x;
  if (i < 12*128)       wcat[i] = x2hw[i];
  else if (i < 44*128)  wcat[i] = h2hw[i - 12*128];
  else if (i < 44*128+128) bsum[i-44*128] = x2hb[i-44*128] + h2hb[i-44*128];
}

// ---------------- fused z-compute + LDS gather + sigmoid : history xg ----------------
__global__ __launch_bounds__(1024)
void k_xg_hist(const float* __restrict__ pm25, const float* __restrict__ feat,
               const float* __restrict__ cw, const float* __restrict__ cb,
               const int* __restrict__ ptr, const int2* __restrict__ epack,
               float* __restrict__ xg){
  __shared__ float zl[Nn*2];           // 32 KB
  f32x2* zl2 = (f32x2*)zl;
  int s = blockIdx.x;                  // t*32 + b
  int t = s >> 5, b = s & 31;
  int tid = threadIdx.x;
  const float* fb = feat + ((size_t)(b*TTC + t)*Nn)*9;
  const float* pb = pm25 + (size_t)(b*HISTC + t)*Nn;
  float sv[4][2];
  #pragma unroll
  for (int p=0;p<4;++p){
    int n = tid + p*1024;
    float x[10];
    x[0] = pb[n];
    #pragma unroll
    for (int f=0; f<9; ++f) x[1+f] = fb[(size_t)n*9+f];
    float z0=0.f, z1=0.f, s0=cb[0], s1=cb[1];
    #pragma unroll
    for (int f=0; f<10; ++f){
      s0 += x[f]*cw[f*2+0];      s1 += x[f]*cw[f*2+1];
      z0 += x[f]*cw[20+f*2+0];   z1 += x[f]*cw[20+f*2+1];
    }
    zl2[n] = (f32x2){z0, z1};
    sv[p][0]=s0; sv[p][1]=s1;
  }
  __syncthreads();
  float* xgb = xg + (size_t)s*Nn*2;
  #pragma unroll
  for (int p=0;p<4;++p){
    int n = tid + p*1024;
    int p0 = ptr[n], p1 = ptr[n+1];
    f32x2 a = {sv[p][0], sv[p][1]};
    for (int i=p0;i<p1;++i){
      int2 e = epack[i];
      float w = __int_as_float(e.y);
      a = __builtin_elementwise_fma((f32x2){w,w}, zl2[e.x], a);
    }
    xgb[n*2]   = sigm_f(a.x);
    xgb[n*2+1] = sigm_f(a.y);
  }
}

// ---------------- gate via v_pk_fma_f32: 2 output cols per instr ----------------
// JOFF2 = gate offset in float2 units (i=0, f=16, g=32, o=48)
template<int JOFF2>
__device__ __forceinline__ void gate2(const f32x2* __restrict__ w2,
                                      const f32x2* __restrict__ b2,
                                      const float (&x)[12], const float (&h)[32],
                                      f32x2 (&acc)[16]){
  #pragma unroll
  for (int u=0;u<16;++u) acc[u] = b2[JOFF2+u];
  #pragma unroll
  for (int k=0;k<12;++k){
    f32x2 xv = {x[k], x[k]};
    const f32x2* wr = w2 + k*64 + JOFF2;
    #pragma unroll
    for (int u=0;u<16;++u) acc[u] = __builtin_elementwise_fma(xv, wr[u], acc[u]);
  }
  #pragma unroll
  for (int k=0;k<32;++k){
    f32x2 hv = {h[k], h[k]};
    const f32x2* wr = w2 + (12+k)*64 + JOFF2;
    #pragma unroll
    for (int u=0;u<16;++u) acc[u] = __builtin_elementwise_fma(hv, wr[u], acc[u]);
  }
}

// full cell: x[12] in, h[32] in/out (f32), c2[16] in/out (f32x2)
__device__ __forceinline__ void cell2(const f32x2* __restrict__ w2,
                                      const f32x2* __restrict__ b2,
                                      const float (&x)[12], float (&h)[32],
                                      f32x2 (&c2)[16]){
  f32x2 acc[16], si[16];
  gate2<16>(w2, b2, x, h, acc);                 // f
  #pragma unroll
  for (int u=0;u<16;++u) c2[u] *= sig2(acc[u]);
  gate2<0>(w2, b2, x, h, acc);                  // i
  #pragma unroll
  for (int u=0;u<16;++u) si[u] = sig2(acc[u]);
  gate2<32>(w2, b2, x, h, acc);                 // g
  #pragma unroll
  for (int u=0;u<16;++u) c2[u] = __builtin_elementwise_fma(si[u], th2(acc[u]), c2[u]);
  gate2<48>(w2, b2, x, h, acc);                 // o (last user of old h)
  #pragma unroll
  for (int u=0;u<16;++u){
    f32x2 hv = sig2(acc[u]) * th2(c2[u]);
    h[2*u] = hv.x; h[2*u+1] = hv.y;
  }
}

// ---------------- persistent history LSTM: lane = row, 16 steps in-register -----
__global__ __launch_bounds__(256,1)
void k_hist(const float* __restrict__ pm25, const float* __restrict__ feat,
            const float* __restrict__ xg,
            const float* __restrict__ wcat, const float* __restrict__ bsum,
            const float* __restrict__ fcw, const float* __restrict__ fcb,
            float* __restrict__ hO, float* __restrict__ cO, float* __restrict__ xn0){
  size_t gr = blockIdx.x*256 + threadIdx.x;     // b*N + n
  int b = (int)(gr >> 12), n = (int)(gr & (Nn-1));
  const float* fb = feat + ((size_t)b*TTC*Nn + n)*9;
  const float* pb = pm25 + (size_t)b*HISTC*Nn + n;
  const f32x2* w2 = (const f32x2*)wcat;
  const f32x2* b2 = (const f32x2*)bsum;

  float h[32]; f32x2 c2[16];
  #pragma unroll
  for (int u=0;u<32;++u) h[u]=0.f;
  #pragma unroll
  for (int u=0;u<16;++u) c2[u]=(f32x2){0.f,0.f};

  float xf[12];
  xf[0] = pb[0];
  #pragma unroll
  for (int f=0;f<9;++f) xf[1+f] = fb[f];
  { float2 g = *(const float2*)&xg[gr*2]; xf[10]=g.x; xf[11]=g.y; }

  #pragma unroll 1
  for (int t=0; t<HISTC; ++t){
    float nxt[12];
    if (t < HISTC-1){                           // prefetch next step's x
      nxt[0] = pb[(size_t)(t+1)*Nn];
      #pragma unroll
      for (int f=0;f<9;++f) nxt[1+f] = fb[(size_t)(t+1)*Nn*9 + f];
      float2 g = *(const float2*)&xg[((size_t)(t+1)*BN + gr)*2];
      nxt[10]=g.x; nxt[11]=g.y;
    }
    cell2(w2, b2, xf, h, c2);
    if (t < HISTC-1){
      #pragma unroll
      for (int k=0;k<12;++k) xf[k] = nxt[k];
    }
  }

  float4* hp = (float4*)(hO + gr*32);
  #pragma unroll
  for (int v=0;v<8;++v) hp[v] = make_float4(h[4*v],h[4*v+1],h[4*v+2],h[4*v+3]);
  float4* cp = (float4*)(cO + gr*32);
  #pragma unroll
  for (int v=0;v<8;++v)
    cp[v] = make_float4(c2[2*v].x,c2[2*v].y,c2[2*v+1].x,c2[2*v+1].y);
  float r = fcb[0];
  #pragma unroll
  for (int u=0;u<32;++u) r = fmaf(h[u], fcw[u], r);
  xn0[gr] = r;
}

// ---------------- fused pred step: z in LDS + gather + LSTM + fc ----------------
// 512 blocks: b = blk&31, sub = blk>>5
__global__ __launch_bounds__(256,1)
void k_pred(const float* __restrict__ feat, const float* __restrict__ xnI,
            const float* __restrict__ cw, const float* __restrict__ cb,
            const int* __restrict__ ptr, const int2* __restrict__ epack,
            const float* __restrict__ wcat, const float* __restrict__ bsum,
            const float* __restrict__ fcw, const float* __restrict__ fcb,
            float* __restrict__ hO, float* __restrict__ cO,
            float* __restrict__ xnO, float* __restrict__ out, int t){
  __shared__ float zl[Nn*2];                    // 32 KB
  f32x2* zl2 = (f32x2*)zl;
  int blk = blockIdx.x;
  int b = blk & 31, sub = blk >> 5;
  int tid = threadIdx.x;
  const float* fb = feat + ((size_t)(b*TTC + t)*Nn)*9;
  const float* xb = xnI + (size_t)b*Nn;
  const f32x2* w2 = (const f32x2*)wcat;
  const f32x2* b2 = (const f32x2*)bsum;

  float xf[10]; float sown0=0.f, sown1=0.f;
  #pragma unroll 1
  for (int p=0;p<16;++p){
    int n = p*256 + tid;
    float x[10];
    x[0] = xb[n];
    #pragma unroll
    for (int f=0;f<9;++f) x[1+f] = fb[(size_t)n*9+f];
    float z0=0.f, z1=0.f, s0=cb[0], s1=cb[1];
    #pragma unroll
    for (int f=0;f<10;++f){
      s0 += x[f]*cw[f*2+0];      s1 += x[f]*cw[f*2+1];
      z0 += x[f]*cw[20+f*2+0];   z1 += x[f]*cw[20+f*2+1];
    }
    zl2[n] = (f32x2){z0, z1};
    if (p == sub){
      sown0 = s0; sown1 = s1;
      #pragma unroll
      for (int f=0;f<10;++f) xf[f] = x[f];
    }
  }
  __syncthreads();

  int n = sub*256 + tid;
  size_t gr = (size_t)b*Nn + n;
  int p0 = ptr[n], p1 = ptr[n+1];
  f32x2 a = {sown0, sown1};
  for (int i=p0;i<p1;++i){
    int2 e = epack[i];
    float w = __int_as_float(e.y);
    a = __builtin_elementwise_fma((f32x2){w,w}, zl2[e.x], a);
  }

  float x[12];
  #pragma unroll
  for (int f=0;f<10;++f) x[f] = xf[f];
  x[10] = sigm_f(a.x); x[11] = sigm_f(a.y);

  float h[32]; f32x2 c2[16];
  const float4* hI = (const float4*)(hO + gr*32);
  #pragma unroll
  for (int v=0;v<8;++v){
    float4 hv = hI[v]; h[4*v]=hv.x; h[4*v+1]=hv.y; h[4*v+2]=hv.z; h[4*v+3]=hv.w;
  }
  const float4* cI = (const float4*)(cO + gr*32);
  #pragma unroll
  for (int v=0;v<8;++v){
    float4 cv = cI[v];
    c2[2*v]   = (f32x2){cv.x, cv.y};
    c2[2*v+1] = (f32x2){cv.z, cv.w};
  }

  cell2(w2, b2, x, h, c2);

  float4* hp = (float4*)(hO + gr*32);
  #pragma unroll
  for (int v=0;v<8;++v) hp[v] = make_float4(h[4*v],h[4*v+1],h[4*v+2],h[4*v+3]);
  float4* cp = (float4*)(cO + gr*32);
  #pragma unroll
  for (int v=0;v<8;++v)
    cp[v] = make_float4(c2[2*v].x,c2[2*v].y,c2[2*v+1].x,c2[2*v+1].y);
  float r = fcb[0];
  #pragma unroll
  for (int u=0;u<32;++u) r = fmaf(h[u], fcw[u], r);
  xnO[gr] = r;
  out[(size_t)b*PREDC*Nn + n] = r;              // out pre-offset by tp*Nn
}

// ---------------- host ----------------
extern "C" void kernel_launch(void* const* d_in, const int* in_sizes, int n_in,
                              void* d_out, int out_size, void* d_ws, size_t ws_size,
                              hipStream_t stream){
  const float* pm25 = (const float*)d_in[0];
  const float* feat = (const float*)d_in[1];
  const int*   ei   = (const int*)d_in[2];
  const float* cw   = (const float*)d_in[3];
  const float* cb   = (const float*)d_in[4];
  const float* x2hw = (const float*)d_in[5];
  const float* x2hb = (const float*)d_in[6];
  const float* h2hw = (const float*)d_in[7];
  const float* h2hb = (const float*)d_in[8];
  const float* fcw  = (const float*)d_in[9];
  const float* fcb  = (const float*)d_in[10];
  float* out = (float*)d_out;

  char* w = (char*)d_ws;
  size_t off = 0;
  auto take = [&](size_t bytes)->char*{
    char* r = w + off; off += (bytes + 255) & ~(size_t)255; return r;
  };
  int*   deg   = (int*)  take(Nn*4);
  int*   cnt   = (int*)  take(Nn*4);
  int*   fillc = (int*)  take(Nn*4);
  int*   ptr   = (int*)  take((Nn+1)*4);
  float* dis   = (float*)take(Nn*4);
  int2*  epack = (int2*) take(EC*8);
  float* wcat  = (float*)take(44*128*4);
  float* bsum  = (float*)take(128*4);
  float* sbuf  = (float*)take((size_t)HISTC*BN*2*4);   // hist xg
  float* hbuf  = (float*)take((size_t)BN*32*4);
  float* cbuf  = (float*)take((size_t)BN*32*4);
  float* xn0   = (float*)take((size_t)BN*4);
  float* xn1   = (float*)take((size_t)BN*4);

  (void)hipMemsetAsync(deg, 0, Nn*4*3, stream);  // deg,cnt,fillc adjacent

  k_deg <<<EC/256, 256, 0, stream>>>(ei, deg, cnt);
  k_dis <<<Nn/256, 256, 0, stream>>>(deg, dis);
  k_scan<<<1, 1024, 0, stream>>>(cnt, ptr);
  k_fill<<<EC/256, 256, 0, stream>>>(ei, dis, ptr, fillc, epack);
  k_prep<<<23, 256, 0, stream>>>(x2hw, h2hw, x2hb, h2hb, wcat, bsum);

  k_xg_hist<<<HISTC*Bb, 1024, 0, stream>>>(pm25, feat, cw, cb, ptr, epack, sbuf);
  k_hist<<<BN/256, 256, 0, stream>>>(pm25, feat, sbuf, wcat, bsum, fcw, fcb,
                                     hbuf, cbuf, xn0);

  for (int tp = 0; tp < PREDC; ++tp){
    int t = HISTC + tp;
    float* xi = (tp & 1) ? xn1 : xn0;
    float* xo = (tp & 1) ? xn0 : xn1;
    k_pred<<<Bb*16, 256, 0, stream>>>(feat, xi, cw, cb, ptr, epack,
                                      wcat, bsum, fcw, fcb, hbuf, cbuf,
                                      xo, out + (size_t)tp*Nn, t);
  }
}

// Round 7
// 752.655 us; speedup vs baseline: 2.1678x; 2.1678x over previous
//
#include <hip/hip_runtime.h>
#include <math.h>

#define Bb    32
#define Nn    4096
#define HISTC 16
#define PREDC 8
#define TTC   24
#define EC    65536
#define BN    (Bb*Nn)          // 131072

typedef float f32x2 __attribute__((ext_vector_type(2)));
typedef float f32x4 __attribute__((ext_vector_type(4)));
typedef __fp16 f16x8 __attribute__((ext_vector_type(8)));
typedef __fp16 fp16v2 __attribute__((ext_vector_type(2)));

__device__ __forceinline__ float sigm_f(float x){
  return __builtin_amdgcn_rcpf(1.f + __expf(-x));
}
__device__ __forceinline__ float tanh_f(float x){
  return fmaf(-2.f, __builtin_amdgcn_rcpf(1.f + __expf(2.f*x)), 1.f);
}
__device__ __forceinline__ unsigned pk2(float a, float b){
  fp16v2 v = __builtin_amdgcn_cvt_pkrtz(a, b);
  return __builtin_bit_cast(unsigned, v);
}
__device__ __forceinline__ f32x4 mfma16(uint4 a, uint4 b, f32x4 c){
  return __builtin_amdgcn_mfma_f32_16x16x32_f16(
      __builtin_bit_cast(f16x8, a), __builtin_bit_cast(f16x8, b), c, 0, 0, 0);
}

// ---------------- CSR build ----------------
__global__ void k_deg(const int* __restrict__ ei, int* deg, int* cnt){
  int e = blockIdx.x*blockDim.x + threadIdx.x;
  if (e < EC){ atomicAdd(&deg[ei[e]],1); atomicAdd(&cnt[ei[EC+e]],1); }
}
__global__ void k_dis(const int* __restrict__ deg, float* dis){
  int n = blockIdx.x*blockDim.x + threadIdx.x;
  if (n < Nn) dis[n] = deg[n] > 0 ? rsqrtf((float)deg[n]) : 0.f;
}
__global__ void k_scan(const int* __restrict__ cnt, int* ptr){
  __shared__ int sd[1024];
  int t = threadIdx.x;
  int c0=cnt[4*t], c1=cnt[4*t+1], c2=cnt[4*t+2], c3=cnt[4*t+3];
  int s = c0+c1+c2+c3;
  sd[t] = s; __syncthreads();
  for (int off=1; off<1024; off<<=1){
    int v = (t>=off) ? sd[t-off] : 0;
    __syncthreads();
    sd[t] += v;
    __syncthreads();
  }
  int excl = sd[t]-s;
  ptr[4*t]=excl; ptr[4*t+1]=excl+c0; ptr[4*t+2]=excl+c0+c1; ptr[4*t+3]=excl+c0+c1+c2;
  if (t==1023) ptr[4096]=sd[1023];
}
__global__ void k_fill(const int* __restrict__ ei, const float* __restrict__ dis,
                       const int* __restrict__ ptr, int* fillc, int2* __restrict__ epack){
  int e = blockIdx.x*blockDim.x + threadIdx.x;
  if (e < EC){
    int s = ei[e], d = ei[EC+e];
    int pos = ptr[d] + atomicAdd(&fillc[d],1);
    epack[pos] = make_int2(s, __float_as_int(-dis[s]*dis[d]));
  }
}

// ---------------- build B-fragments (f16) for the gate GEMM ----------------
// frag f = kt*8+ct; lane; j:  k = kt*32 + (lane>>4)*8 + j, col = ct*16 + (lane&15)
// k<12: x2h rows; k==12: bias (x=1 slot); 13..31: 0; 32..63: h2h rows
__global__ void k_prep(const float* __restrict__ x2hw, const float* __restrict__ h2hw,
                       const float* __restrict__ x2hb, const float* __restrict__ h2hb,
                       _Float16* __restrict__ wfrag){
  int i = blockIdx.x*256 + threadIdx.x;     // 8192 total
  int f = i >> 9, lane = (i >> 3) & 63, j = i & 7;
  int kt = f >> 3, ct = f & 7;
  int k = kt*32 + (lane>>4)*8 + j;
  int col = ct*16 + (lane&15);
  float v;
  if (k < 12)       v = x2hw[k*128 + col];
  else if (k == 12) v = x2hb[col] + h2hb[col];
  else if (k < 32)  v = 0.f;
  else              v = h2hw[(k-32)*128 + col];
  wfrag[f*512 + lane*8 + j] = (_Float16)v;
}

// ---------------- fused z-compute + LDS gather + sigmoid : history xg ----------------
__global__ __launch_bounds__(1024)
void k_xg_hist(const float* __restrict__ pm25, const float* __restrict__ feat,
               const float* __restrict__ cw, const float* __restrict__ cb,
               const int* __restrict__ ptr, const int2* __restrict__ epack,
               float* __restrict__ xg){
  __shared__ float zl[Nn*2];           // 32 KB
  f32x2* zl2 = (f32x2*)zl;
  int s = blockIdx.x;                  // t*32 + b
  int t = s >> 5, b = s & 31;
  int tid = threadIdx.x;
  const float* fb = feat + ((size_t)(b*TTC + t)*Nn)*9;
  const float* pb = pm25 + (size_t)(b*HISTC + t)*Nn;
  float sv[4][2];
  #pragma unroll
  for (int p=0;p<4;++p){
    int n = tid + p*1024;
    float x[10];
    x[0] = pb[n];
    #pragma unroll
    for (int f=0; f<9; ++f) x[1+f] = fb[(size_t)n*9+f];
    float z0=0.f, z1=0.f, s0=cb[0], s1=cb[1];
    #pragma unroll
    for (int f=0; f<10; ++f){
      s0 += x[f]*cw[f*2+0];      s1 += x[f]*cw[f*2+1];
      z0 += x[f]*cw[20+f*2+0];   z1 += x[f]*cw[20+f*2+1];
    }
    zl2[n] = (f32x2){z0, z1};
    sv[p][0]=s0; sv[p][1]=s1;
  }
  __syncthreads();
  float* xgb = xg + (size_t)s*Nn*2;
  #pragma unroll
  for (int p=0;p<4;++p){
    int n = tid + p*1024;
    int p0 = ptr[n], p1 = ptr[n+1];
    f32x2 a = {sv[p][0], sv[p][1]};
    for (int i=p0;i<p1;++i){
      int2 e = epack[i];
      float w = __int_as_float(e.y);
      a = __builtin_elementwise_fma((f32x2){w,w}, zl2[e.x], a);
    }
    xgb[n*2]   = sigm_f(a.x);
    xgb[n*2+1] = sigm_f(a.y);
  }
}

// ---------------- fused z + gather : prediction xg (one block per batch b) ------
__global__ __launch_bounds__(1024)
void k_xg_pred(const float* __restrict__ xnI, const float* __restrict__ feat,
               const float* __restrict__ cw, const float* __restrict__ cb,
               const int* __restrict__ ptr, const int2* __restrict__ epack,
               float* __restrict__ xgp, int t){
  __shared__ float zl[Nn*2];
  f32x2* zl2 = (f32x2*)zl;
  int b = blockIdx.x;
  int tid = threadIdx.x;
  const float* fb = feat + ((size_t)(b*TTC + t)*Nn)*9;
  const float* xb = xnI + (size_t)b*Nn;
  float sv[4][2];
  #pragma unroll
  for (int p=0;p<4;++p){
    int n = tid + p*1024;
    float x[10];
    x[0] = xb[n];
    #pragma unroll
    for (int f=0;f<9;++f) x[1+f] = fb[(size_t)n*9+f];
    float z0=0.f, z1=0.f, s0=cb[0], s1=cb[1];
    #pragma unroll
    for (int f=0;f<10;++f){
      s0 += x[f]*cw[f*2+0];      s1 += x[f]*cw[f*2+1];
      z0 += x[f]*cw[20+f*2+0];   z1 += x[f]*cw[20+f*2+1];
    }
    zl2[n] = (f32x2){z0, z1};
    sv[p][0]=s0; sv[p][1]=s1;
  }
  __syncthreads();
  #pragma unroll
  for (int p=0;p<4;++p){
    int n = tid + p*1024;
    int p0 = ptr[n], p1 = ptr[n+1];
    f32x2 a = {sv[p][0], sv[p][1]};
    for (int i=p0;i<p1;++i){
      int2 e = epack[i];
      float w = __int_as_float(e.y);
      a = __builtin_elementwise_fma((f32x2){w,w}, zl2[e.x], a);
    }
    float2 r; r.x = sigm_f(a.x); r.y = sigm_f(a.y);
    *(float2*)&xgp[((size_t)b*Nn + n)*2] = r;
  }
}

// ---------------- MFMA LSTM pointwise helper ----------------
// acc[8] C-layout: lane holds rows m=(l>>4)*4+r, cols (l&15)+{0,16} of each gate.
#define POINTWISE(r)                                                            \
  c0[r] = fmaf(sigm_f(acc[0][r]), tanh_f(acc[4][r]), sigm_f(acc[2][r])*c0[r]);  \
  h0[r] = sigm_f(acc[6][r])*tanh_f(c0[r]);                                      \
  c1[r] = fmaf(sigm_f(acc[1][r]), tanh_f(acc[5][r]), sigm_f(acc[3][r])*c1[r]);  \
  h1[r] = sigm_f(acc[7][r])*tanh_f(c1[r]);

// ---------------- persistent history LSTM: wave = 16 rows, 16 steps, MFMA ------
__global__ __launch_bounds__(256,1)
void k_hist(const float* __restrict__ pm25, const float* __restrict__ feat,
            const float* __restrict__ xg, const uint4* __restrict__ wfrag,
            const float* __restrict__ fcw, const float* __restrict__ fcb,
            uint4* __restrict__ hfragO, float4* __restrict__ cO,
            float* __restrict__ xn0){
  __shared__ __align__(16) _Float16 hl[4][16][40];
  int lane = threadIdx.x & 63, w = threadIdx.x >> 6;
  int gw = blockIdx.x*4 + w;                 // global wave id
  int r0 = gw*16;                            // first global row of this wave's tile
  int b = r0 >> 12, n0 = r0 & (Nn-1);
  int l15 = lane & 15, g4 = lane >> 4;
  int n = n0 + l15;                          // row this lane loads x for (A layout)
  const float* pb = pm25 + (size_t)b*HISTC*Nn + n;
  const float* fb = feat + ((size_t)b*TTC*Nn + n)*9;

  uint4 bw[16];
  #pragma unroll
  for (int f=0; f<16; ++f) bw[f] = wfrag[f*64 + lane];
  float fw0 = fcw[l15], fw1 = fcw[l15+16];

  uint4 ah = make_uint4(0,0,0,0);            // h = 0 (A-fragment form)
  float c0[4]={0,0,0,0}, c1[4]={0,0,0,0};
  float h0[4], h1[4];
  const f32x4 zacc = {0.f,0.f,0.f,0.f};

  #pragma unroll 1
  for (int t=0; t<HISTC; ++t){
    uint4 ax;
    const float* fbt = fb + (size_t)t*Nn*9;
    if (g4 == 0){
      float x0 = pb[(size_t)t*Nn];
      ax.x = pk2(x0, fbt[0]);    ax.y = pk2(fbt[1], fbt[2]);
      ax.z = pk2(fbt[3], fbt[4]); ax.w = pk2(fbt[5], fbt[6]);
    } else if (g4 == 1){
      float2 gg = *(const float2*)&xg[((size_t)t*BN + r0 + l15)*2];
      ax.x = pk2(fbt[7], fbt[8]); ax.y = pk2(gg.x, gg.y);
      ax.z = pk2(1.f, 0.f);       ax.w = 0u;
    } else {
      ax = make_uint4(0,0,0,0);
    }

    f32x4 acc[8];
    #pragma unroll
    for (int ct=0; ct<8; ++ct) acc[ct] = mfma16(ax, bw[ct], zacc);
    #pragma unroll
    for (int ct=0; ct<8; ++ct) acc[ct] = mfma16(ah, bw[8+ct], acc[ct]);

    POINTWISE(0) POINTWISE(1) POINTWISE(2) POINTWISE(3)

    #pragma unroll
    for (int r=0;r<4;++r){
      hl[w][g4*4+r][l15]    = (_Float16)h0[r];
      hl[w][g4*4+r][l15+16] = (_Float16)h1[r];
    }
    asm volatile("s_waitcnt lgkmcnt(0)" ::: "memory");
    ah = *(const uint4*)&hl[w][l15][g4*8];   // new h in A-fragment form
  }

  hfragO[(size_t)gw*64 + lane] = ah;
  cO[((size_t)gw*64 + lane)*2]   = make_float4(c0[0],c0[1],c0[2],c0[3]);
  cO[((size_t)gw*64 + lane)*2+1] = make_float4(c1[0],c1[1],c1[2],c1[3]);
  #pragma unroll
  for (int r=0;r<4;++r){
    float p = fmaf(h0[r], fw0, h1[r]*fw1);
    p += __shfl_xor(p, 1, 16); p += __shfl_xor(p, 2, 16);
    p += __shfl_xor(p, 4, 16); p += __shfl_xor(p, 8, 16);
    if (l15 == 0) xn0[r0 + g4*4 + r] = p + fcb[0];
  }
}

// ---------------- one prediction LSTM step (MFMA cell) ----------------
__global__ __launch_bounds__(256,1)
void k_cell1(const float* __restrict__ feat, const float* __restrict__ xnI,
             const float* __restrict__ xgp, const uint4* __restrict__ wfrag,
             const float* __restrict__ fcw, const float* __restrict__ fcb,
             uint4* __restrict__ hfrag, float4* __restrict__ cS,
             float* __restrict__ xnO, float* __restrict__ out, int t){
  __shared__ __align__(16) _Float16 hl[4][16][40];
  int lane = threadIdx.x & 63, w = threadIdx.x >> 6;
  int gw = blockIdx.x*4 + w;
  int r0 = gw*16;
  int b = r0 >> 12, n0 = r0 & (Nn-1);
  int l15 = lane & 15, g4 = lane >> 4;
  int n = n0 + l15;
  const float* fbt = feat + ((size_t)(b*TTC + t)*Nn + n)*9;

  uint4 bw[16];
  #pragma unroll
  for (int f=0; f<16; ++f) bw[f] = wfrag[f*64 + lane];
  float fw0 = fcw[l15], fw1 = fcw[l15+16];

  uint4 ah = hfrag[(size_t)gw*64 + lane];
  float4 cv0 = cS[((size_t)gw*64 + lane)*2];
  float4 cv1 = cS[((size_t)gw*64 + lane)*2+1];
  float c0[4] = {cv0.x, cv0.y, cv0.z, cv0.w};
  float c1[4] = {cv1.x, cv1.y, cv1.z, cv1.w};
  float h0[4], h1[4];
  const f32x4 zacc = {0.f,0.f,0.f,0.f};

  uint4 ax;
  if (g4 == 0){
    float x0 = xnI[r0 + l15];
    ax.x = pk2(x0, fbt[0]);     ax.y = pk2(fbt[1], fbt[2]);
    ax.z = pk2(fbt[3], fbt[4]); ax.w = pk2(fbt[5], fbt[6]);
  } else if (g4 == 1){
    float2 gg = *(const float2*)&xgp[(size_t)(r0 + l15)*2];
    ax.x = pk2(fbt[7], fbt[8]); ax.y = pk2(gg.x, gg.y);
    ax.z = pk2(1.f, 0.f);       ax.w = 0u;
  } else {
    ax = make_uint4(0,0,0,0);
  }

  f32x4 acc[8];
  #pragma unroll
  for (int ct=0; ct<8; ++ct) acc[ct] = mfma16(ax, bw[ct], zacc);
  #pragma unroll
  for (int ct=0; ct<8; ++ct) acc[ct] = mfma16(ah, bw[8+ct], acc[ct]);

  POINTWISE(0) POINTWISE(1) POINTWISE(2) POINTWISE(3)

  #pragma unroll
  for (int r=0;r<4;++r){
    hl[w][g4*4+r][l15]    = (_Float16)h0[r];
    hl[w][g4*4+r][l15+16] = (_Float16)h1[r];
  }
  asm volatile("s_waitcnt lgkmcnt(0)" ::: "memory");
  ah = *(const uint4*)&hl[w][l15][g4*8];

  hfrag[(size_t)gw*64 + lane] = ah;
  cS[((size_t)gw*64 + lane)*2]   = make_float4(c0[0],c0[1],c0[2],c0[3]);
  cS[((size_t)gw*64 + lane)*2+1] = make_float4(c1[0],c1[1],c1[2],c1[3]);
  #pragma unroll
  for (int r=0;r<4;++r){
    float p = fmaf(h0[r], fw0, h1[r]*fw1);
    p += __shfl_xor(p, 1, 16); p += __shfl_xor(p, 2, 16);
    p += __shfl_xor(p, 4, 16); p += __shfl_xor(p, 8, 16);
    if (l15 == 0){
      float rr = p + fcb[0];
      int nrow = n0 + g4*4 + r;
      xnO[r0 + g4*4 + r] = rr;
      out[(size_t)b*PREDC*Nn + nrow] = rr;   // out pre-offset by tp*Nn
    }
  }
}

// ---------------- host ----------------
extern "C" void kernel_launch(void* const* d_in, const int* in_sizes, int n_in,
                              void* d_out, int out_size, void* d_ws, size_t ws_size,
                              hipStream_t stream){
  const float* pm25 = (const float*)d_in[0];
  const float* feat = (const float*)d_in[1];
  const int*   ei   = (const int*)d_in[2];
  const float* cw   = (const float*)d_in[3];
  const float* cb   = (const float*)d_in[4];
  const float* x2hw = (const float*)d_in[5];
  const float* x2hb = (const float*)d_in[6];
  const float* h2hw = (const float*)d_in[7];
  const float* h2hb = (const float*)d_in[8];
  const float* fcw  = (const float*)d_in[9];
  const float* fcb  = (const float*)d_in[10];
  float* out = (float*)d_out;

  char* w = (char*)d_ws;
  size_t off = 0;
  auto take = [&](size_t bytes)->char*{
    char* r = w + off; off += (bytes + 255) & ~(size_t)255; return r;
  };
  int*      deg   = (int*)      take(Nn*4);
  int*      cnt   = (int*)      take(Nn*4);
  int*      fillc = (int*)      take(Nn*4);
  int*      ptr   = (int*)      take((Nn+1)*4);
  float*    dis   = (float*)    take(Nn*4);
  int2*     epack = (int2*)     take(EC*8);
  _Float16* wfrag = (_Float16*) take(16*512*2);            // 16 KB fragment table
  float*    sbuf  = (float*)    take((size_t)HISTC*BN*2*4);// hist xg
  float*    xgp   = (float*)    take((size_t)BN*2*4);      // pred xg
  uint4*    hfrag = (uint4*)    take((size_t)(BN/16)*64*16);
  float4*   cbuf  = (float4*)   take((size_t)(BN/16)*64*2*16);
  float*    xn0   = (float*)    take((size_t)BN*4);
  float*    xn1   = (float*)    take((size_t)BN*4);

  (void)hipMemsetAsync(deg, 0, Nn*4*3, stream);  // deg,cnt,fillc adjacent

  k_deg <<<EC/256, 256, 0, stream>>>(ei, deg, cnt);
  k_dis <<<Nn/256, 256, 0, stream>>>(deg, dis);
  k_scan<<<1, 1024, 0, stream>>>(cnt, ptr);
  k_fill<<<EC/256, 256, 0, stream>>>(ei, dis, ptr, fillc, epack);
  k_prep<<<32, 256, 0, stream>>>(x2hw, h2hw, x2hb, h2hb, wfrag);

  k_xg_hist<<<HISTC*Bb, 1024, 0, stream>>>(pm25, feat, cw, cb, ptr, epack, sbuf);
  k_hist<<<BN/64, 256, 0, stream>>>(pm25, feat, sbuf, (const uint4*)wfrag,
                                    fcw, fcb, hfrag, cbuf, xn0);

  for (int tp = 0; tp < PREDC; ++tp){
    int t = HISTC + tp;
    float* xi = (tp & 1) ? xn1 : xn0;
    float* xo = (tp & 1) ? xn0 : xn1;
    k_xg_pred<<<Bb, 1024, 0, stream>>>(xi, feat, cw, cb, ptr, epack, xgp, t);
    k_cell1<<<BN/64, 256, 0, stream>>>(feat, xi, xgp, (const uint4*)wfrag,
                                       fcw, fcb, hfrag, cbuf,
                                       xo, out + (size_t)tp*Nn, t);
  }
}

// Round 9
// 708.446 us; speedup vs baseline: 2.3031x; 1.0624x over previous
//
#include <hip/hip_runtime.h>
#include <math.h>

#define Bb    32
#define Nn    4096
#define HISTC 16
#define PREDC 8
#define TTC   24
#define EC    65536
#define BN    (Bb*Nn)          // 131072

typedef float f32x2 __attribute__((ext_vector_type(2)));
typedef float f32x4 __attribute__((ext_vector_type(4)));
typedef __fp16 f16x8 __attribute__((ext_vector_type(8)));
typedef __fp16 fp16v2 __attribute__((ext_vector_type(2)));

__device__ __forceinline__ float sigm_f(float x){
  return __builtin_amdgcn_rcpf(1.f + __expf(-x));
}
__device__ __forceinline__ float tanh_f(float x){
  return fmaf(-2.f, __builtin_amdgcn_rcpf(1.f + __expf(2.f*x)), 1.f);
}
__device__ __forceinline__ unsigned pk2(float a, float b){
  fp16v2 v = __builtin_amdgcn_cvt_pkrtz(a, b);
  return __builtin_bit_cast(unsigned, v);
}
__device__ __forceinline__ f32x4 mfma16(uint4 a, uint4 b, f32x4 c){
  return __builtin_amdgcn_mfma_f32_16x16x32_f16(
      __builtin_bit_cast(f16x8, a), __builtin_bit_cast(f16x8, b), c, 0, 0, 0);
}

// ---------------- CSR build ----------------
__global__ void k_deg(const int* __restrict__ ei, int* deg, int* cnt){
  int e = blockIdx.x*blockDim.x + threadIdx.x;
  if (e < EC){ atomicAdd(&deg[ei[e]],1); atomicAdd(&cnt[ei[EC+e]],1); }
}
__global__ void k_dis(const int* __restrict__ deg, float* dis){
  int n = blockIdx.x*blockDim.x + threadIdx.x;
  if (n < Nn) dis[n] = deg[n] > 0 ? rsqrtf((float)deg[n]) : 0.f;
}
__global__ void k_scan(const int* __restrict__ cnt, int* ptr){
  __shared__ int sd[1024];
  int t = threadIdx.x;
  int c0=cnt[4*t], c1=cnt[4*t+1], c2=cnt[4*t+2], c3=cnt[4*t+3];
  int s = c0+c1+c2+c3;
  sd[t] = s; __syncthreads();
  for (int off=1; off<1024; off<<=1){
    int v = (t>=off) ? sd[t-off] : 0;
    __syncthreads();
    sd[t] += v;
    __syncthreads();
  }
  int excl = sd[t]-s;
  ptr[4*t]=excl; ptr[4*t+1]=excl+c0; ptr[4*t+2]=excl+c0+c1; ptr[4*t+3]=excl+c0+c1+c2;
  if (t==1023) ptr[4096]=sd[1023];
}
// CSR epack (src,norm) sorted by dst  +  eall (src,dst,norm) original order
__global__ void k_fill(const int* __restrict__ ei, const float* __restrict__ dis,
                       const int* __restrict__ ptr, int* fillc,
                       int2* __restrict__ epack, int4* __restrict__ eall){
  int e = blockIdx.x*blockDim.x + threadIdx.x;
  if (e < EC){
    int s = ei[e], d = ei[EC+e];
    int nb = __float_as_int(-dis[s]*dis[d]);
    int pos = ptr[d] + atomicAdd(&fillc[d],1);
    epack[pos] = make_int2(s, nb);
    eall[e] = make_int4(s, d, nb, 0);
  }
}

// ---------------- build B-fragments (f16) for the gate GEMM ----------------
// frag f = kt*8+ct; lane; j:  k = kt*32 + (lane>>4)*8 + j, col = ct*16 + (lane&15)
__global__ void k_prep(const float* __restrict__ x2hw, const float* __restrict__ h2hw,
                       const float* __restrict__ x2hb, const float* __restrict__ h2hb,
                       _Float16* __restrict__ wfrag){
  int i = blockIdx.x*256 + threadIdx.x;     // 8192 total
  int f = i >> 9, lane = (i >> 3) & 63, j = i & 7;
  int kt = f >> 3, ct = f & 7;
  int k = kt*32 + (lane>>4)*8 + j;
  int col = ct*16 + (lane&15);
  float v;
  if (k < 12)       v = x2hw[k*128 + col];
  else if (k == 12) v = x2hb[col] + h2hb[col];
  else if (k < 32)  v = 0.f;
  else              v = h2hw[(k-32)*128 + col];
  wfrag[f*512 + lane*8 + j] = (_Float16)v;
}

// ---------------- hist xg: z in LDS + EDGE-PARALLEL atomic gather ----------------
__global__ __launch_bounds__(1024)
void k_xg_hist(const float* __restrict__ pm25, const float* __restrict__ feat,
               const float* __restrict__ cw, const float* __restrict__ cb,
               const int4* __restrict__ eall, float* __restrict__ xg){
  __shared__ float zl[Nn*2];           // z pairs, 32 KB
  __shared__ float al[Nn*2];           // accum pairs, 32 KB
  f32x2* zl2 = (f32x2*)zl;
  int s = blockIdx.x;                  // t*32 + b
  int t = s >> 5, b = s & 31;
  int tid = threadIdx.x;
  const float* fb = feat + ((size_t)(b*TTC + t)*Nn)*9;
  const float* pb = pm25 + (size_t)(b*HISTC + t)*Nn;
  #pragma unroll
  for (int p=0;p<4;++p){
    int n = tid + p*1024;
    float x[10];
    x[0] = pb[n];
    #pragma unroll
    for (int f=0; f<9; ++f) x[1+f] = fb[(size_t)n*9+f];
    float z0=0.f, z1=0.f, s0=cb[0], s1=cb[1];
    #pragma unroll
    for (int f=0; f<10; ++f){
      s0 += x[f]*cw[f*2+0];      s1 += x[f]*cw[f*2+1];
      z0 += x[f]*cw[20+f*2+0];   z1 += x[f]*cw[20+f*2+1];
    }
    zl2[n] = (f32x2){z0, z1};
    al[n*2] = s0; al[n*2+1] = s1;
  }
  __syncthreads();
  #pragma unroll 1
  for (int i = tid; i < EC; i += 1024){       // coalesced 16B edge loads
    int4 e = eall[i];
    float w = __int_as_float(e.z);
    f32x2 zv = zl2[e.x];
    atomicAdd(&al[e.y*2],   w*zv.x);
    atomicAdd(&al[e.y*2+1], w*zv.y);
  }
  __syncthreads();
  float* xgb = xg + (size_t)s*Nn*2;
  #pragma unroll
  for (int p=0;p<4;++p){
    int n = tid + p*1024;
    float2 r; r.x = sigm_f(al[n*2]); r.y = sigm_f(al[n*2+1]);
    *(float2*)&xgb[n*2] = r;
  }
}

// ---------------- pred z: zbuf[r] = x @ W1 (coalesced, tiny) ----------------
__global__ __launch_bounds__(256)
void k_z(const float* __restrict__ xnI, const float* __restrict__ feat,
         const float* __restrict__ cw, f32x2* __restrict__ zbuf, int t){
  int r = blockIdx.x*256 + threadIdx.x;       // b*Nn + n
  int b = r >> 12, n = r & (Nn-1);
  const float* fp = feat + ((size_t)(b*TTC + t)*Nn + n)*9;
  float x[10];
  x[0] = xnI[r];
  #pragma unroll
  for (int f=0;f<9;++f) x[1+f] = fp[f];
  float z0=0.f, z1=0.f;
  #pragma unroll
  for (int f=0;f<10;++f){
    z0 += x[f]*cw[20+f*2+0]; z1 += x[f]*cw[20+f*2+1];
  }
  zbuf[r] = (f32x2){z0, z1};
}

// ---------------- MFMA LSTM pointwise helper ----------------
#define POINTWISE(r)                                                            \
  c0[r] = fmaf(sigm_f(acc[0][r]), tanh_f(acc[4][r]), sigm_f(acc[2][r])*c0[r]);  \
  h0[r] = sigm_f(acc[6][r])*tanh_f(c0[r]);                                      \
  c1[r] = fmaf(sigm_f(acc[1][r]), tanh_f(acc[5][r]), sigm_f(acc[3][r])*c1[r]);  \
  h1[r] = sigm_f(acc[7][r])*tanh_f(c1[r]);

// ---------------- persistent history LSTM (unchanged from r7) ----------------
__global__ __launch_bounds__(256,1)
void k_hist(const float* __restrict__ pm25, const float* __restrict__ feat,
            const float* __restrict__ xg, const uint4* __restrict__ wfrag,
            const float* __restrict__ fcw, const float* __restrict__ fcb,
            uint4* __restrict__ hfragO, float4* __restrict__ cO,
            float* __restrict__ xn0){
  __shared__ __align__(16) _Float16 hl[4][16][40];
  int lane = threadIdx.x & 63, w = threadIdx.x >> 6;
  int gw = blockIdx.x*4 + w;
  int r0 = gw*16;
  int b = r0 >> 12, n0 = r0 & (Nn-1);
  int l15 = lane & 15, g4 = lane >> 4;
  int n = n0 + l15;
  const float* pb = pm25 + (size_t)b*HISTC*Nn + n;
  const float* fb = feat + ((size_t)b*TTC*Nn + n)*9;

  uint4 bw[16];
  #pragma unroll
  for (int f=0; f<16; ++f) bw[f] = wfrag[f*64 + lane];
  float fw0 = fcw[l15], fw1 = fcw[l15+16];

  uint4 ah = make_uint4(0,0,0,0);
  float c0[4]={0,0,0,0}, c1[4]={0,0,0,0};
  float h0[4], h1[4];
  const f32x4 zacc = {0.f,0.f,0.f,0.f};

  #pragma unroll 1
  for (int t=0; t<HISTC; ++t){
    uint4 ax;
    const float* fbt = fb + (size_t)t*Nn*9;
    if (g4 == 0){
      float x0 = pb[(size_t)t*Nn];
      ax.x = pk2(x0, fbt[0]);    ax.y = pk2(fbt[1], fbt[2]);
      ax.z = pk2(fbt[3], fbt[4]); ax.w = pk2(fbt[5], fbt[6]);
    } else if (g4 == 1){
      float2 gg = *(const float2*)&xg[((size_t)t*BN + r0 + l15)*2];
      ax.x = pk2(fbt[7], fbt[8]); ax.y = pk2(gg.x, gg.y);
      ax.z = pk2(1.f, 0.f);       ax.w = 0u;
    } else {
      ax = make_uint4(0,0,0,0);
    }

    f32x4 acc[8];
    #pragma unroll
    for (int ct=0; ct<8; ++ct) acc[ct] = mfma16(ax, bw[ct], zacc);
    #pragma unroll
    for (int ct=0; ct<8; ++ct) acc[ct] = mfma16(ah, bw[8+ct], acc[ct]);

    POINTWISE(0) POINTWISE(1) POINTWISE(2) POINTWISE(3)

    #pragma unroll
    for (int r=0;r<4;++r){
      hl[w][g4*4+r][l15]    = (_Float16)h0[r];
      hl[w][g4*4+r][l15+16] = (_Float16)h1[r];
    }
    asm volatile("s_waitcnt lgkmcnt(0)" ::: "memory");
    ah = *(const uint4*)&hl[w][l15][g4*8];
  }

  hfragO[(size_t)gw*64 + lane] = ah;
  cO[((size_t)gw*64 + lane)*2]   = make_float4(c0[0],c0[1],c0[2],c0[3]);
  cO[((size_t)gw*64 + lane)*2+1] = make_float4(c1[0],c1[1],c1[2],c1[3]);
  #pragma unroll
  for (int r=0;r<4;++r){
    float p = fmaf(h0[r], fw0, h1[r]*fw1);
    p += __shfl_xor(p, 1, 16); p += __shfl_xor(p, 2, 16);
    p += __shfl_xor(p, 4, 16); p += __shfl_xor(p, 8, 16);
    if (l15 == 0) xn0[r0 + g4*4 + r] = p + fcb[0];
  }
}

// ---------------- fused pred step: z-slice LDS + in-wave gather + MFMA cell ----
__global__ __launch_bounds__(256,1)
void k_pred_cell(const float* __restrict__ feat, const float* __restrict__ xnI,
                 const f32x2* __restrict__ zbuf,
                 const int* __restrict__ ptr, const int2* __restrict__ epack,
                 const float* __restrict__ cw, const float* __restrict__ cb,
                 const uint4* __restrict__ wfrag,
                 const float* __restrict__ fcw, const float* __restrict__ fcb,
                 uint4* __restrict__ hfrag, float4* __restrict__ cS,
                 float* __restrict__ xnO, float* __restrict__ out, int t){
  __shared__ f32x2 zl2[Nn];                   // 32 KB: this batch-slice's z
  __shared__ __align__(16) _Float16 hl[4][16][40];
  int tid = threadIdx.x;
  int lane = tid & 63, w = tid >> 6;
  int gw = blockIdx.x*4 + w;
  int r0 = gw*16;
  int b = r0 >> 12, n0 = r0 & (Nn-1);
  int l15 = lane & 15, g4 = lane >> 4;

  {                                           // stage z slice (coalesced)
    const f32x2* zsrc = zbuf + (size_t)b*Nn;
    #pragma unroll
    for (int k=0;k<16;++k) zl2[tid + k*256] = zsrc[tid + k*256];
  }

  uint4 bw[16];
  #pragma unroll
  for (int f=0; f<16; ++f) bw[f] = wfrag[f*64 + lane];
  float fw0 = fcw[l15], fw1 = fcw[l15+16];

  uint4 ah = hfrag[(size_t)gw*64 + lane];
  float4 cv0 = cS[((size_t)gw*64 + lane)*2];
  float4 cv1 = cS[((size_t)gw*64 + lane)*2+1];
  float c0[4] = {cv0.x, cv0.y, cv0.z, cv0.w};
  float c1[4] = {cv1.x, cv1.y, cv1.z, cv1.w};
  float h0[4], h1[4];
  const f32x4 zacc = {0.f,0.f,0.f,0.f};

  // per-row x loads + partial s (= Tx0 part of cheb pre-activation)
  int nrow = n0 + l15;                        // node within slice
  const float* fbt = feat + ((size_t)(b*TTC + t)*Nn + n0 + l15)*9;   // FIXED (was r0+l15: OOB)
  float xv[9]; float a0 = 0.f, a1 = 0.f; float x0 = 0.f;
  if (g4 == 0){
    x0 = xnI[r0 + l15];
    #pragma unroll
    for (int f=0;f<7;++f) xv[f] = fbt[f];
    a0 = x0*cw[0]; a1 = x0*cw[1];
    #pragma unroll
    for (int f=0;f<7;++f){ a0 += xv[f]*cw[(f+1)*2]; a1 += xv[f]*cw[(f+1)*2+1]; }
  } else if (g4 == 1){
    xv[7] = fbt[7]; xv[8] = fbt[8];
    a0 = cb[0] + xv[7]*cw[16] + xv[8]*cw[18];
    a1 = cb[1] + xv[7]*cw[17] + xv[8]*cw[19];
  }

  __syncthreads();                            // zl2 ready

  // in-wave edge gather: 4 lanes (g4) split row nrow's CSR range
  {
    int p0 = ptr[nrow], p1 = ptr[nrow+1];
    for (int i = p0 + g4; i < p1; i += 4){
      int2 e = epack[i];
      float wgt = __int_as_float(e.y);
      f32x2 zv = zl2[e.x];
      a0 = fmaf(wgt, zv.x, a0);
      a1 = fmaf(wgt, zv.y, a1);
    }
    a0 += __shfl_xor(a0, 16); a0 += __shfl_xor(a0, 32);
    a1 += __shfl_xor(a1, 16); a1 += __shfl_xor(a1, 32);
  }
  float xg0 = sigm_f(a0), xg1 = sigm_f(a1);

  uint4 ax;
  if (g4 == 0){
    ax.x = pk2(x0, xv[0]);     ax.y = pk2(xv[1], xv[2]);
    ax.z = pk2(xv[3], xv[4]);  ax.w = pk2(xv[5], xv[6]);
  } else if (g4 == 1){
    ax.x = pk2(xv[7], xv[8]);  ax.y = pk2(xg0, xg1);
    ax.z = pk2(1.f, 0.f);      ax.w = 0u;
  } else {
    ax = make_uint4(0,0,0,0);
  }

  f32x4 acc[8];
  #pragma unroll
  for (int ct=0; ct<8; ++ct) acc[ct] = mfma16(ax, bw[ct], zacc);
  #pragma unroll
  for (int ct=0; ct<8; ++ct) acc[ct] = mfma16(ah, bw[8+ct], acc[ct]);

  POINTWISE(0) POINTWISE(1) POINTWISE(2) POINTWISE(3)

  #pragma unroll
  for (int r=0;r<4;++r){
    hl[w][g4*4+r][l15]    = (_Float16)h0[r];
    hl[w][g4*4+r][l15+16] = (_Float16)h1[r];
  }
  asm volatile("s_waitcnt lgkmcnt(0)" ::: "memory");
  ah = *(const uint4*)&hl[w][l15][g4*8];

  hfrag[(size_t)gw*64 + lane] = ah;
  cS[((size_t)gw*64 + lane)*2]   = make_float4(c0[0],c0[1],c0[2],c0[3]);
  cS[((size_t)gw*64 + lane)*2+1] = make_float4(c1[0],c1[1],c1[2],c1[3]);
  #pragma unroll
  for (int r=0;r<4;++r){
    float p = fmaf(h0[r], fw0, h1[r]*fw1);
    p += __shfl_xor(p, 1, 16); p += __shfl_xor(p, 2, 16);
    p += __shfl_xor(p, 4, 16); p += __shfl_xor(p, 8, 16);
    if (l15 == 0){
      float rr = p + fcb[0];
      int nr = n0 + g4*4 + r;
      xnO[r0 + g4*4 + r] = rr;
      out[(size_t)b*PREDC*Nn + nr] = rr;      // out pre-offset by tp*Nn
    }
  }
}

// ---------------- host ----------------
extern "C" void kernel_launch(void* const* d_in, const int* in_sizes, int n_in,
                              void* d_out, int out_size, void* d_ws, size_t ws_size,
                              hipStream_t stream){
  const float* pm25 = (const float*)d_in[0];
  const float* feat = (const float*)d_in[1];
  const int*   ei   = (const int*)d_in[2];
  const float* cw   = (const float*)d_in[3];
  const float* cb   = (const float*)d_in[4];
  const float* x2hw = (const float*)d_in[5];
  const float* x2hb = (const float*)d_in[6];
  const float* h2hw = (const float*)d_in[7];
  const float* h2hb = (const float*)d_in[8];
  const float* fcw  = (const float*)d_in[9];
  const float* fcb  = (const float*)d_in[10];
  float* out = (float*)d_out;

  char* w = (char*)d_ws;
  size_t off = 0;
  auto take = [&](size_t bytes)->char*{
    char* r = w + off; off += (bytes + 255) & ~(size_t)255; return r;
  };
  int*      deg   = (int*)      take(Nn*4);
  int*      cnt   = (int*)      take(Nn*4);
  int*      fillc = (int*)      take(Nn*4);
  int*      ptr   = (int*)      take((Nn+1)*4);
  float*    dis   = (float*)    take(Nn*4);
  int2*     epack = (int2*)     take(EC*8);
  int4*     eall  = (int4*)     take(EC*16);
  _Float16* wfrag = (_Float16*) take(16*512*2);
  float*    sbuf  = (float*)    take((size_t)HISTC*BN*2*4);   // hist xg
  f32x2*    zbuf  = (f32x2*)    take((size_t)BN*8);           // pred z
  uint4*    hfrag = (uint4*)    take((size_t)(BN/16)*64*16);
  float4*   cbuf  = (float4*)   take((size_t)(BN/16)*64*2*16);
  float*    xn0   = (float*)    take((size_t)BN*4);
  float*    xn1   = (float*)    take((size_t)BN*4);

  (void)hipMemsetAsync(deg, 0, Nn*4*3, stream);   // deg,cnt,fillc adjacent

  k_deg <<<EC/256, 256, 0, stream>>>(ei, deg, cnt);
  k_dis <<<Nn/256, 256, 0, stream>>>(deg, dis);
  k_scan<<<1, 1024, 0, stream>>>(cnt, ptr);
  k_fill<<<EC/256, 256, 0, stream>>>(ei, dis, ptr, fillc, epack, eall);
  k_prep<<<32, 256, 0, stream>>>(x2hw, h2hw, x2hb, h2hb, wfrag);

  k_xg_hist<<<HISTC*Bb, 1024, 0, stream>>>(pm25, feat, cw, cb, eall, sbuf);
  k_hist<<<BN/64, 256, 0, stream>>>(pm25, feat, sbuf, (const uint4*)wfrag,
                                    fcw, fcb, hfrag, cbuf, xn0);

  for (int tp = 0; tp < PREDC; ++tp){
    int t = HISTC + tp;
    float* xi = (tp & 1) ? xn1 : xn0;
    float* xo = (tp & 1) ? xn0 : xn1;
    k_z<<<BN/256, 256, 0, stream>>>(xi, feat, cw, zbuf, t);
    k_pred_cell<<<BN/64, 256, 0, stream>>>(feat, xi, zbuf, ptr, epack, cw, cb,
                                           (const uint4*)wfrag, fcw, fcb,
                                           hfrag, cbuf, xo, out + (size_t)tp*Nn, t);
  }
}

// Round 10
// 580.964 us; speedup vs baseline: 2.8084x; 1.2194x over previous
//
#include <hip/hip_runtime.h>
#include <math.h>

#define Bb    32
#define Nn    4096
#define HISTC 16
#define PREDC 8
#define TTC   24
#define EC    65536
#define BN    (Bb*Nn)          // 131072

typedef float f32x2 __attribute__((ext_vector_type(2)));
typedef float f32x4 __attribute__((ext_vector_type(4)));
typedef __fp16 f16x8 __attribute__((ext_vector_type(8)));
typedef __fp16 fp16v2 __attribute__((ext_vector_type(2)));

__device__ __forceinline__ float sigm_f(float x){
  return __builtin_amdgcn_rcpf(1.f + __expf(-x));
}
__device__ __forceinline__ float tanh_f(float x){
  return fmaf(-2.f, __builtin_amdgcn_rcpf(1.f + __expf(2.f*x)), 1.f);
}
__device__ __forceinline__ unsigned pk2(float a, float b){
  fp16v2 v = __builtin_amdgcn_cvt_pkrtz(a, b);
  return __builtin_bit_cast(unsigned, v);
}
__device__ __forceinline__ f32x4 mfma16(uint4 a, uint4 b, f32x4 c){
  return __builtin_amdgcn_mfma_f32_16x16x32_f16(
      __builtin_bit_cast(f16x8, a), __builtin_bit_cast(f16x8, b), c, 0, 0, 0);
}

// ---------------- CSR build ----------------
__global__ void k_deg(const int* __restrict__ ei, int* deg, int* cnt){
  int e = blockIdx.x*blockDim.x + threadIdx.x;
  if (e < EC){ atomicAdd(&deg[ei[e]],1); atomicAdd(&cnt[ei[EC+e]],1); }
}
__global__ void k_dis(const int* __restrict__ deg, float* dis){
  int n = blockIdx.x*blockDim.x + threadIdx.x;
  if (n < Nn) dis[n] = deg[n] > 0 ? rsqrtf((float)deg[n]) : 0.f;
}
__global__ void k_scan(const int* __restrict__ cnt, int* ptr){
  __shared__ int sd[1024];
  int t = threadIdx.x;
  int c0=cnt[4*t], c1=cnt[4*t+1], c2=cnt[4*t+2], c3=cnt[4*t+3];
  int s = c0+c1+c2+c3;
  sd[t] = s; __syncthreads();
  for (int off=1; off<1024; off<<=1){
    int v = (t>=off) ? sd[t-off] : 0;
    __syncthreads();
    sd[t] += v;
    __syncthreads();
  }
  int excl = sd[t]-s;
  ptr[4*t]=excl; ptr[4*t+1]=excl+c0; ptr[4*t+2]=excl+c0+c1; ptr[4*t+3]=excl+c0+c1+c2;
  if (t==1023) ptr[4096]=sd[1023];
}
__global__ void k_fill(const int* __restrict__ ei, const float* __restrict__ dis,
                       const int* __restrict__ ptr, int* fillc, int2* __restrict__ epack){
  int e = blockIdx.x*blockDim.x + threadIdx.x;
  if (e < EC){
    int s = ei[e], d = ei[EC+e];
    int pos = ptr[d] + atomicAdd(&fillc[d],1);
    epack[pos] = make_int2(s, __float_as_int(-dis[s]*dis[d]));
  }
}

// ---------------- build B-fragments (f16) for the gate GEMM ----------------
// frag f = kt*8+ct; lane; j:  k = kt*32 + (lane>>4)*8 + j, col = ct*16 + (lane&15)
__global__ void k_prep(const float* __restrict__ x2hw, const float* __restrict__ h2hw,
                       const float* __restrict__ x2hb, const float* __restrict__ h2hb,
                       _Float16* __restrict__ wfrag){
  int i = blockIdx.x*256 + threadIdx.x;     // 8192 total
  int f = i >> 9, lane = (i >> 3) & 63, j = i & 7;
  int kt = f >> 3, ct = f & 7;
  int k = kt*32 + (lane>>4)*8 + j;
  int col = ct*16 + (lane&15);
  float v;
  if (k < 12)       v = x2hw[k*128 + col];
  else if (k == 12) v = x2hb[col] + h2hb[col];
  else if (k < 32)  v = 0.f;
  else              v = h2hw[(k-32)*128 + col];
  wfrag[f*512 + lane*8 + j] = (_Float16)v;
}

// ---------------- hist z: zbufH[t][b][n] = x @ W1 (coalesced) ----------------
__global__ __launch_bounds__(256)
void k_zh(const float* __restrict__ pm25, const float* __restrict__ feat,
          const float* __restrict__ cw, f32x2* __restrict__ zbufH){
  int r = blockIdx.x*256 + threadIdx.x;     // t*BN + bn
  int t = r >> 17, bn = r & (BN-1);
  int b = bn >> 12, n = bn & (Nn-1);
  const float* fp = feat + ((size_t)(b*TTC + t)*Nn + n)*9;
  float x[10];
  x[0] = pm25[(size_t)(b*HISTC + t)*Nn + n];
  #pragma unroll
  for (int f=0;f<9;++f) x[1+f] = fp[f];
  float z0=0.f, z1=0.f;
  #pragma unroll
  for (int f=0;f<10;++f){
    z0 += x[f]*cw[20+f*2+0]; z1 += x[f]*cw[20+f*2+1];
  }
  zbufH[((size_t)(t*Bb + b))*Nn + n] = (f32x2){z0, z1};
}

// ---------------- pred z: zbuf[r] = x @ W1 (coalesced, tiny) ----------------
__global__ __launch_bounds__(256)
void k_z(const float* __restrict__ xnI, const float* __restrict__ feat,
         const float* __restrict__ cw, f32x2* __restrict__ zbuf, int t){
  int r = blockIdx.x*256 + threadIdx.x;       // b*Nn + n
  int b = r >> 12, n = r & (Nn-1);
  const float* fp = feat + ((size_t)(b*TTC + t)*Nn + n)*9;
  float x[10];
  x[0] = xnI[r];
  #pragma unroll
  for (int f=0;f<9;++f) x[1+f] = fp[f];
  float z0=0.f, z1=0.f;
  #pragma unroll
  for (int f=0;f<10;++f){
    z0 += x[f]*cw[20+f*2+0]; z1 += x[f]*cw[20+f*2+1];
  }
  zbuf[r] = (f32x2){z0, z1};
}

// ---------------- MFMA LSTM pointwise helper ----------------
#define POINTWISE(r)                                                            \
  c0[r] = fmaf(sigm_f(acc[0][r]), tanh_f(acc[4][r]), sigm_f(acc[2][r])*c0[r]);  \
  h0[r] = sigm_f(acc[6][r])*tanh_f(c0[r]);                                      \
  c1[r] = fmaf(sigm_f(acc[1][r]), tanh_f(acc[5][r]), sigm_f(acc[3][r])*c1[r]);  \
  h1[r] = sigm_f(acc[7][r])*tanh_f(c1[r]);

// ---------------- persistent history LSTM with FUSED xg gather ----------------
__global__ __launch_bounds__(256,1)
void k_hist(const float* __restrict__ pm25, const float* __restrict__ feat,
            const f32x2* __restrict__ zbufH,
            const int* __restrict__ ptr, const int2* __restrict__ epack,
            const float* __restrict__ cw, const float* __restrict__ cb,
            const uint4* __restrict__ wfrag,
            const float* __restrict__ fcw, const float* __restrict__ fcb,
            uint4* __restrict__ hfragO, float4* __restrict__ cO,
            float* __restrict__ xn0){
  __shared__ f32x2 zl2[Nn];                   // 32 KB: z slice for step t
  __shared__ __align__(16) _Float16 hl[4][16][40];
  int tid = threadIdx.x;
  int lane = tid & 63, w = tid >> 6;
  int gw = blockIdx.x*4 + w;
  int r0 = gw*16;
  int b = r0 >> 12, n0 = r0 & (Nn-1);
  int l15 = lane & 15, g4 = lane >> 4;
  int nrow = n0 + l15;
  const float* pb = pm25 + (size_t)b*HISTC*Nn + nrow;
  const float* fb = feat + ((size_t)b*TTC*Nn + nrow)*9;

  uint4 bw[16];
  #pragma unroll
  for (int f=0; f<16; ++f) bw[f] = wfrag[f*64 + lane];
  float fw0 = fcw[l15], fw1 = fcw[l15+16];
  int p0 = ptr[nrow], p1 = ptr[nrow+1];       // t-invariant

  uint4 ah = make_uint4(0,0,0,0);
  float c0[4]={0,0,0,0}, c1[4]={0,0,0,0};
  float h0[4], h1[4];
  const f32x4 zacc = {0.f,0.f,0.f,0.f};

  #pragma unroll 1
  for (int t=0; t<HISTC; ++t){
    {                                         // stage z slice (coalesced)
      const f32x2* zsrc = zbufH + ((size_t)(t*Bb + b))*Nn;
      #pragma unroll
      for (int k=0;k<16;++k) zl2[tid + k*256] = zsrc[tid + k*256];
    }
    // per-row x loads + partial s (x@W0+cb split across g4=0,1)
    const float* fbt = fb + (size_t)t*Nn*9;
    float xv[9]; float a0 = 0.f, a1 = 0.f; float x0 = 0.f;
    if (g4 == 0){
      x0 = pb[(size_t)t*Nn];
      #pragma unroll
      for (int f=0;f<7;++f) xv[f] = fbt[f];
      a0 = x0*cw[0]; a1 = x0*cw[1];
      #pragma unroll
      for (int f=0;f<7;++f){ a0 += xv[f]*cw[(f+1)*2]; a1 += xv[f]*cw[(f+1)*2+1]; }
    } else if (g4 == 1){
      xv[7] = fbt[7]; xv[8] = fbt[8];
      a0 = cb[0] + xv[7]*cw[16] + xv[8]*cw[18];
      a1 = cb[1] + xv[7]*cw[17] + xv[8]*cw[19];
    }
    __syncthreads();                          // zl2 ready

    // in-wave edge gather: 4 lanes (g4) split row nrow's CSR range
    for (int i = p0 + g4; i < p1; i += 4){
      int2 e = epack[i];
      float wgt = __int_as_float(e.y);
      f32x2 zv = zl2[e.x];
      a0 = fmaf(wgt, zv.x, a0);
      a1 = fmaf(wgt, zv.y, a1);
    }
    a0 += __shfl_xor(a0, 16); a0 += __shfl_xor(a0, 32);
    a1 += __shfl_xor(a1, 16); a1 += __shfl_xor(a1, 32);
    float xg0 = sigm_f(a0), xg1 = sigm_f(a1);
    __syncthreads();                          // gather done; zl2 may be restaged

    uint4 ax;
    if (g4 == 0){
      ax.x = pk2(x0, xv[0]);     ax.y = pk2(xv[1], xv[2]);
      ax.z = pk2(xv[3], xv[4]);  ax.w = pk2(xv[5], xv[6]);
    } else if (g4 == 1){
      ax.x = pk2(xv[7], xv[8]);  ax.y = pk2(xg0, xg1);
      ax.z = pk2(1.f, 0.f);      ax.w = 0u;
    } else {
      ax = make_uint4(0,0,0,0);
    }

    f32x4 acc[8];
    #pragma unroll
    for (int ct=0; ct<8; ++ct) acc[ct] = mfma16(ax, bw[ct], zacc);
    #pragma unroll
    for (int ct=0; ct<8; ++ct) acc[ct] = mfma16(ah, bw[8+ct], acc[ct]);

    POINTWISE(0) POINTWISE(1) POINTWISE(2) POINTWISE(3)

    #pragma unroll
    for (int r=0;r<4;++r){
      hl[w][g4*4+r][l15]    = (_Float16)h0[r];
      hl[w][g4*4+r][l15+16] = (_Float16)h1[r];
    }
    asm volatile("s_waitcnt lgkmcnt(0)" ::: "memory");
    ah = *(const uint4*)&hl[w][l15][g4*8];
  }

  hfragO[(size_t)gw*64 + lane] = ah;
  cO[((size_t)gw*64 + lane)*2]   = make_float4(c0[0],c0[1],c0[2],c0[3]);
  cO[((size_t)gw*64 + lane)*2+1] = make_float4(c1[0],c1[1],c1[2],c1[3]);
  #pragma unroll
  for (int r=0;r<4;++r){
    float p = fmaf(h0[r], fw0, h1[r]*fw1);
    p += __shfl_xor(p, 1, 16); p += __shfl_xor(p, 2, 16);
    p += __shfl_xor(p, 4, 16); p += __shfl_xor(p, 8, 16);
    if (l15 == 0) xn0[r0 + g4*4 + r] = p + fcb[0];
  }
}

// ---------------- fused pred step: z-slice LDS + in-wave gather + MFMA cell ----
__global__ __launch_bounds__(256,1)
void k_pred_cell(const float* __restrict__ feat, const float* __restrict__ xnI,
                 const f32x2* __restrict__ zbuf,
                 const int* __restrict__ ptr, const int2* __restrict__ epack,
                 const float* __restrict__ cw, const float* __restrict__ cb,
                 const uint4* __restrict__ wfrag,
                 const float* __restrict__ fcw, const float* __restrict__ fcb,
                 uint4* __restrict__ hfrag, float4* __restrict__ cS,
                 float* __restrict__ xnO, float* __restrict__ out, int t){
  __shared__ f32x2 zl2[Nn];                   // 32 KB: this batch-slice's z
  __shared__ __align__(16) _Float16 hl[4][16][40];
  int tid = threadIdx.x;
  int lane = tid & 63, w = tid >> 6;
  int gw = blockIdx.x*4 + w;
  int r0 = gw*16;
  int b = r0 >> 12, n0 = r0 & (Nn-1);
  int l15 = lane & 15, g4 = lane >> 4;

  {                                           // stage z slice (coalesced)
    const f32x2* zsrc = zbuf + (size_t)b*Nn;
    #pragma unroll
    for (int k=0;k<16;++k) zl2[tid + k*256] = zsrc[tid + k*256];
  }

  uint4 bw[16];
  #pragma unroll
  for (int f=0; f<16; ++f) bw[f] = wfrag[f*64 + lane];
  float fw0 = fcw[l15], fw1 = fcw[l15+16];

  uint4 ah = hfrag[(size_t)gw*64 + lane];
  float4 cv0 = cS[((size_t)gw*64 + lane)*2];
  float4 cv1 = cS[((size_t)gw*64 + lane)*2+1];
  float c0[4] = {cv0.x, cv0.y, cv0.z, cv0.w};
  float c1[4] = {cv1.x, cv1.y, cv1.z, cv1.w};
  float h0[4], h1[4];
  const f32x4 zacc = {0.f,0.f,0.f,0.f};

  int nrow = n0 + l15;
  const float* fbt = feat + ((size_t)(b*TTC + t)*Nn + n0 + l15)*9;
  float xv[9]; float a0 = 0.f, a1 = 0.f; float x0 = 0.f;
  if (g4 == 0){
    x0 = xnI[r0 + l15];
    #pragma unroll
    for (int f=0;f<7;++f) xv[f] = fbt[f];
    a0 = x0*cw[0]; a1 = x0*cw[1];
    #pragma unroll
    for (int f=0;f<7;++f){ a0 += xv[f]*cw[(f+1)*2]; a1 += xv[f]*cw[(f+1)*2+1]; }
  } else if (g4 == 1){
    xv[7] = fbt[7]; xv[8] = fbt[8];
    a0 = cb[0] + xv[7]*cw[16] + xv[8]*cw[18];
    a1 = cb[1] + xv[7]*cw[17] + xv[8]*cw[19];
  }

  __syncthreads();                            // zl2 ready

  {
    int p0 = ptr[nrow], p1 = ptr[nrow+1];
    for (int i = p0 + g4; i < p1; i += 4){
      int2 e = epack[i];
      float wgt = __int_as_float(e.y);
      f32x2 zv = zl2[e.x];
      a0 = fmaf(wgt, zv.x, a0);
      a1 = fmaf(wgt, zv.y, a1);
    }
    a0 += __shfl_xor(a0, 16); a0 += __shfl_xor(a0, 32);
    a1 += __shfl_xor(a1, 16); a1 += __shfl_xor(a1, 32);
  }
  float xg0 = sigm_f(a0), xg1 = sigm_f(a1);

  uint4 ax;
  if (g4 == 0){
    ax.x = pk2(x0, xv[0]);     ax.y = pk2(xv[1], xv[2]);
    ax.z = pk2(xv[3], xv[4]);  ax.w = pk2(xv[5], xv[6]);
  } else if (g4 == 1){
    ax.x = pk2(xv[7], xv[8]);  ax.y = pk2(xg0, xg1);
    ax.z = pk2(1.f, 0.f);      ax.w = 0u;
  } else {
    ax = make_uint4(0,0,0,0);
  }

  f32x4 acc[8];
  #pragma unroll
  for (int ct=0; ct<8; ++ct) acc[ct] = mfma16(ax, bw[ct], zacc);
  #pragma unroll
  for (int ct=0; ct<8; ++ct) acc[ct] = mfma16(ah, bw[8+ct], acc[ct]);

  POINTWISE(0) POINTWISE(1) POINTWISE(2) POINTWISE(3)

  #pragma unroll
  for (int r=0;r<4;++r){
    hl[w][g4*4+r][l15]    = (_Float16)h0[r];
    hl[w][g4*4+r][l15+16] = (_Float16)h1[r];
  }
  asm volatile("s_waitcnt lgkmcnt(0)" ::: "memory");
  ah = *(const uint4*)&hl[w][l15][g4*8];

  hfrag[(size_t)gw*64 + lane] = ah;
  cS[((size_t)gw*64 + lane)*2]   = make_float4(c0[0],c0[1],c0[2],c0[3]);
  cS[((size_t)gw*64 + lane)*2+1] = make_float4(c1[0],c1[1],c1[2],c1[3]);
  #pragma unroll
  for (int r=0;r<4;++r){
    float p = fmaf(h0[r], fw0, h1[r]*fw1);
    p += __shfl_xor(p, 1, 16); p += __shfl_xor(p, 2, 16);
    p += __shfl_xor(p, 4, 16); p += __shfl_xor(p, 8, 16);
    if (l15 == 0){
      float rr = p + fcb[0];
      int nr = n0 + g4*4 + r;
      xnO[r0 + g4*4 + r] = rr;
      out[(size_t)b*PREDC*Nn + nr] = rr;      // out pre-offset by tp*Nn
    }
  }
}

// ---------------- host ----------------
extern "C" void kernel_launch(void* const* d_in, const int* in_sizes, int n_in,
                              void* d_out, int out_size, void* d_ws, size_t ws_size,
                              hipStream_t stream){
  const float* pm25 = (const float*)d_in[0];
  const float* feat = (const float*)d_in[1];
  const int*   ei   = (const int*)d_in[2];
  const float* cw   = (const float*)d_in[3];
  const float* cb   = (const float*)d_in[4];
  const float* x2hw = (const float*)d_in[5];
  const float* x2hb = (const float*)d_in[6];
  const float* h2hw = (const float*)d_in[7];
  const float* h2hb = (const float*)d_in[8];
  const float* fcw  = (const float*)d_in[9];
  const float* fcb  = (const float*)d_in[10];
  float* out = (float*)d_out;

  char* w = (char*)d_ws;
  size_t off = 0;
  auto take = [&](size_t bytes)->char*{
    char* r = w + off; off += (bytes + 255) & ~(size_t)255; return r;
  };
  int*      deg   = (int*)      take(Nn*4);
  int*      cnt   = (int*)      take(Nn*4);
  int*      fillc = (int*)      take(Nn*4);
  int*      ptr   = (int*)      take((Nn+1)*4);
  float*    dis   = (float*)    take(Nn*4);
  int2*     epack = (int2*)     take(EC*8);
  _Float16* wfrag = (_Float16*) take(16*512*2);
  f32x2*    zbufH = (f32x2*)    take((size_t)HISTC*BN*8);   // hist z slices
  f32x2*    zbuf  = (f32x2*)    take((size_t)BN*8);         // pred z
  uint4*    hfrag = (uint4*)    take((size_t)(BN/16)*64*16);
  float4*   cbuf  = (float4*)   take((size_t)(BN/16)*64*2*16);
  float*    xn0   = (float*)    take((size_t)BN*4);
  float*    xn1   = (float*)    take((size_t)BN*4);

  (void)hipMemsetAsync(deg, 0, Nn*4*3, stream);   // deg,cnt,fillc adjacent

  k_deg <<<EC/256, 256, 0, stream>>>(ei, deg, cnt);
  k_dis <<<Nn/256, 256, 0, stream>>>(deg, dis);
  k_scan<<<1, 1024, 0, stream>>>(cnt, ptr);
  k_fill<<<EC/256, 256, 0, stream>>>(ei, dis, ptr, fillc, epack);
  k_prep<<<32, 256, 0, stream>>>(x2hw, h2hw, x2hb, h2hb, wfrag);

  k_zh<<<(HISTC*BN)/256, 256, 0, stream>>>(pm25, feat, cw, zbufH);
  k_hist<<<BN/64, 256, 0, stream>>>(pm25, feat, zbufH, ptr, epack, cw, cb,
                                    (const uint4*)wfrag, fcw, fcb,
                                    hfrag, cbuf, xn0);

  for (int tp = 0; tp < PREDC; ++tp){
    int t = HISTC + tp;
    float* xi = (tp & 1) ? xn1 : xn0;
    float* xo = (tp & 1) ? xn0 : xn1;
    k_z<<<BN/256, 256, 0, stream>>>(xi, feat, cw, zbuf, t);
    k_pred_cell<<<BN/64, 256, 0, stream>>>(feat, xi, zbuf, ptr, epack, cw, cb,
                                           (const uint4*)wfrag, fcw, fcb,
                                           hfrag, cbuf, xo, out + (size_t)tp*Nn, t);
  }
}

// Round 11
// 436.204 us; speedup vs baseline: 3.7405x; 1.3319x over previous
//
#include <hip/hip_runtime.h>
#include <math.h>

#define Bb    32
#define Nn    4096
#define HISTC 16
#define PREDC 8
#define TTC   24
#define EC    65536
#define BN    (Bb*Nn)          // 131072

typedef float f32x2 __attribute__((ext_vector_type(2)));
typedef float f32x4 __attribute__((ext_vector_type(4)));
typedef __fp16 f16x8 __attribute__((ext_vector_type(8)));
typedef __fp16 fp16v2 __attribute__((ext_vector_type(2)));

__device__ __forceinline__ float sigm_f(float x){
  return __builtin_amdgcn_rcpf(1.f + __expf(-x));
}
__device__ __forceinline__ float tanh_f(float x){
  return fmaf(-2.f, __builtin_amdgcn_rcpf(1.f + __expf(2.f*x)), 1.f);
}
__device__ __forceinline__ unsigned pk2(float a, float b){
  fp16v2 v = __builtin_amdgcn_cvt_pkrtz(a, b);
  return __builtin_bit_cast(unsigned, v);
}
__device__ __forceinline__ f32x4 mfma16(uint4 a, uint4 b, f32x4 c){
  return __builtin_amdgcn_mfma_f32_16x16x32_f16(
      __builtin_bit_cast(f16x8, a), __builtin_bit_cast(f16x8, b), c, 0, 0, 0);
}

// ---------------- CSR build ----------------
__global__ void k_deg(const int* __restrict__ ei, int* deg, int* cnt){
  int e = blockIdx.x*blockDim.x + threadIdx.x;
  if (e < EC){ atomicAdd(&deg[ei[e]],1); atomicAdd(&cnt[ei[EC+e]],1); }
}
__global__ void k_dis(const int* __restrict__ deg, float* dis){
  int n = blockIdx.x*blockDim.x + threadIdx.x;
  if (n < Nn) dis[n] = deg[n] > 0 ? rsqrtf((float)deg[n]) : 0.f;
}
__global__ void k_scan(const int* __restrict__ cnt, int* ptr){
  __shared__ int sd[1024];
  int t = threadIdx.x;
  int c0=cnt[4*t], c1=cnt[4*t+1], c2=cnt[4*t+2], c3=cnt[4*t+3];
  int s = c0+c1+c2+c3;
  sd[t] = s; __syncthreads();
  for (int off=1; off<1024; off<<=1){
    int v = (t>=off) ? sd[t-off] : 0;
    __syncthreads();
    sd[t] += v;
    __syncthreads();
  }
  int excl = sd[t]-s;
  ptr[4*t]=excl; ptr[4*t+1]=excl+c0; ptr[4*t+2]=excl+c0+c1; ptr[4*t+3]=excl+c0+c1+c2;
  if (t==1023) ptr[4096]=sd[1023];
}
__global__ void k_fill(const int* __restrict__ ei, const float* __restrict__ dis,
                       const int* __restrict__ ptr, int* fillc, int2* __restrict__ epack){
  int e = blockIdx.x*blockDim.x + threadIdx.x;
  if (e < EC){
    int s = ei[e], d = ei[EC+e];
    int pos = ptr[d] + atomicAdd(&fillc[d],1);
    epack[pos] = make_int2(s, __float_as_int(-dis[s]*dis[d]));
  }
}

// ---------------- build B-fragments (f16) for the gate GEMM ----------------
__global__ void k_prep(const float* __restrict__ x2hw, const float* __restrict__ h2hw,
                       const float* __restrict__ x2hb, const float* __restrict__ h2hb,
                       _Float16* __restrict__ wfrag){
  int i = blockIdx.x*256 + threadIdx.x;     // 8192 total
  int f = i >> 9, lane = (i >> 3) & 63, j = i & 7;
  int kt = f >> 3, ct = f & 7;
  int k = kt*32 + (lane>>4)*8 + j;
  int col = ct*16 + (lane&15);
  float v;
  if (k < 12)       v = x2hw[k*128 + col];
  else if (k == 12) v = x2hb[col] + h2hb[col];
  else if (k < 32)  v = 0.f;
  else              v = h2hw[(k-32)*128 + col];
  wfrag[f*512 + lane*8 + j] = (_Float16)v;
}

// ---------------- hist z: bufA[t*32+b][n] = x @ W1 (coalesced) ----------------
__global__ __launch_bounds__(256)
void k_zh(const float* __restrict__ pm25, const float* __restrict__ feat,
          const float* __restrict__ cw, f32x2* __restrict__ zbufH){
  int r = blockIdx.x*256 + threadIdx.x;     // t*BN + bn
  int t = r >> 17, bn = r & (BN-1);
  int b = bn >> 12, n = bn & (Nn-1);
  const float* fp = feat + ((size_t)(b*TTC + t)*Nn + n)*9;
  float x[10];
  x[0] = pm25[(size_t)(b*HISTC + t)*Nn + n];
  #pragma unroll
  for (int f=0;f<9;++f) x[1+f] = fp[f];
  float z0=0.f, z1=0.f;
  #pragma unroll
  for (int f=0;f<10;++f){
    z0 += x[f]*cw[20+f*2+0]; z1 += x[f]*cw[20+f*2+1];
  }
  zbufH[((size_t)(t*Bb + b))*Nn + n] = (f32x2){z0, z1};
}

// ---------------- generic tiled transpose of f32x2 matrix [R][C] -> [C][R] ----
__global__ __launch_bounds__(256)
void k_tr(const f32x2* __restrict__ in, f32x2* __restrict__ out, int R, int C){
  __shared__ f32x2 tile[64][65];
  int tilesR = R >> 6;
  int br = blockIdx.x % tilesR, bc = blockIdx.x / tilesR;
  int r0 = br << 6, c0 = bc << 6;
  for (int i=threadIdx.x; i<4096; i+=256){
    int r = i>>6, c = i&63;
    tile[r][c] = in[(size_t)(r0+r)*C + c0+c];
  }
  __syncthreads();
  for (int i=threadIdx.x; i<4096; i+=256){
    int r = i>>6, c = i&63;
    out[(size_t)(c0+r)*R + r0+c] = tile[c][r];
  }
}

// ---------------- dense-row aggregation: aggT[n][:] = sum_e w_e * zT[src_e][:] --
// block = one dst node; 256 threads own the 1024-float row (one float4 each)
__global__ __launch_bounds__(256)
void k_agg(const int* __restrict__ ptr, const int2* __restrict__ epack,
           const float4* __restrict__ zT, float4* __restrict__ aggT){
  int n = blockIdx.x;
  int tid = threadIdx.x;
  int p0 = ptr[n], p1 = ptr[n+1];
  f32x4 acc = {0.f,0.f,0.f,0.f};
  int i = p0;
  for (; i+1 < p1; i += 2){                   // 2-way ILP
    int2 e0 = epack[i], e1 = epack[i+1];
    float w0 = __int_as_float(e0.y), w1 = __int_as_float(e1.y);
    float4 z0 = zT[(size_t)e0.x*256 + tid];
    float4 z1 = zT[(size_t)e1.x*256 + tid];
    acc.x = fmaf(w0, z0.x, acc.x); acc.y = fmaf(w0, z0.y, acc.y);
    acc.z = fmaf(w0, z0.z, acc.z); acc.w = fmaf(w0, z0.w, acc.w);
    acc.x = fmaf(w1, z1.x, acc.x); acc.y = fmaf(w1, z1.y, acc.y);
    acc.z = fmaf(w1, z1.z, acc.z); acc.w = fmaf(w1, z1.w, acc.w);
  }
  if (i < p1){
    int2 e = epack[i];
    float w = __int_as_float(e.y);
    float4 z = zT[(size_t)e.x*256 + tid];
    acc.x = fmaf(w, z.x, acc.x); acc.y = fmaf(w, z.y, acc.y);
    acc.z = fmaf(w, z.z, acc.z); acc.w = fmaf(w, z.w, acc.w);
  }
  aggT[(size_t)n*256 + tid] = make_float4(acc.x, acc.y, acc.z, acc.w);
}

// ---------------- pred feat-z: zf[tp*32+b][n] = feat @ W1[1:] ----------------
__global__ __launch_bounds__(256)
void k_zf(const float* __restrict__ feat, const float* __restrict__ cw,
          f32x2* __restrict__ zf){
  int r = blockIdx.x*256 + threadIdx.x;     // tp*BN + bn
  int tp = r >> 17, bn = r & (BN-1);
  int b = bn >> 12, n = bn & (Nn-1);
  int t = HISTC + tp;
  const float* fp = feat + ((size_t)(b*TTC + t)*Nn + n)*9;
  float z0=0.f, z1=0.f;
  #pragma unroll
  for (int f=0;f<9;++f){
    float v = fp[f];
    z0 += v*cw[20+(f+1)*2+0]; z1 += v*cw[20+(f+1)*2+1];
  }
  zf[((size_t)(tp*Bb + b))*Nn + n] = (f32x2){z0, z1};
}

// ---------------- MFMA LSTM pointwise helper ----------------
#define POINTWISE(r)                                                            \
  c0[r] = fmaf(sigm_f(acc[0][r]), tanh_f(acc[4][r]), sigm_f(acc[2][r])*c0[r]);  \
  h0[r] = sigm_f(acc[6][r])*tanh_f(c0[r]);                                      \
  c1[r] = fmaf(sigm_f(acc[1][r]), tanh_f(acc[5][r]), sigm_f(acc[3][r])*c1[r]);  \
  h1[r] = sigm_f(acc[7][r])*tanh_f(c1[r]);

// ---------------- persistent history LSTM: reads precomputed agg, no barriers --
__global__ __launch_bounds__(256,1)
void k_hist(const float* __restrict__ pm25, const float* __restrict__ feat,
            const f32x2* __restrict__ aggH,
            const float* __restrict__ cw, const float* __restrict__ cb,
            const uint4* __restrict__ wfrag,
            const float* __restrict__ fcw, const float* __restrict__ fcb,
            uint4* __restrict__ hfragO, float4* __restrict__ cO,
            float* __restrict__ xn0){
  __shared__ __align__(16) _Float16 hl[4][16][40];
  int tid = threadIdx.x;
  int lane = tid & 63, w = tid >> 6;
  int gw = blockIdx.x*4 + w;
  int r0 = gw*16;
  int b = r0 >> 12, n0 = r0 & (Nn-1);
  int l15 = lane & 15, g4 = lane >> 4;
  int nrow = n0 + l15;
  const float* pb = pm25 + (size_t)b*HISTC*Nn + nrow;
  const float* fb = feat + ((size_t)b*TTC*Nn + nrow)*9;

  uint4 bw[16];
  #pragma unroll
  for (int f=0; f<16; ++f) bw[f] = wfrag[f*64 + lane];
  float fw0 = fcw[l15], fw1 = fcw[l15+16];

  uint4 ah = make_uint4(0,0,0,0);
  float c0[4]={0,0,0,0}, c1[4]={0,0,0,0};
  float h0[4], h1[4];
  const f32x4 zacc = {0.f,0.f,0.f,0.f};

  #pragma unroll 1
  for (int t=0; t<HISTC; ++t){
    const float* fbt = fb + (size_t)t*Nn*9;
    float xv[9]; float a0 = 0.f, a1 = 0.f; float x0 = 0.f;
    if (g4 == 0){
      x0 = pb[(size_t)t*Nn];
      #pragma unroll
      for (int f=0;f<7;++f) xv[f] = fbt[f];
      a0 = x0*cw[0]; a1 = x0*cw[1];
      #pragma unroll
      for (int f=0;f<7;++f){ a0 += xv[f]*cw[(f+1)*2]; a1 += xv[f]*cw[(f+1)*2+1]; }
    } else if (g4 == 1){
      xv[7] = fbt[7]; xv[8] = fbt[8];
      a0 = cb[0] + xv[7]*cw[16] + xv[8]*cw[18];
      a1 = cb[1] + xv[7]*cw[17] + xv[8]*cw[19];
    } else if (g4 == 2){
      f32x2 ag = aggH[((size_t)(t*Bb + b))*Nn + nrow];
      a0 = ag.x; a1 = ag.y;
    }
    a0 += __shfl_xor(a0, 16); a0 += __shfl_xor(a0, 32);
    a1 += __shfl_xor(a1, 16); a1 += __shfl_xor(a1, 32);
    float xg0 = sigm_f(a0), xg1 = sigm_f(a1);

    uint4 ax;
    if (g4 == 0){
      ax.x = pk2(x0, xv[0]);     ax.y = pk2(xv[1], xv[2]);
      ax.z = pk2(xv[3], xv[4]);  ax.w = pk2(xv[5], xv[6]);
    } else if (g4 == 1){
      ax.x = pk2(xv[7], xv[8]);  ax.y = pk2(xg0, xg1);
      ax.z = pk2(1.f, 0.f);      ax.w = 0u;
    } else {
      ax = make_uint4(0,0,0,0);
    }

    f32x4 acc[8];
    #pragma unroll
    for (int ct=0; ct<8; ++ct) acc[ct] = mfma16(ax, bw[ct], zacc);
    #pragma unroll
    for (int ct=0; ct<8; ++ct) acc[ct] = mfma16(ah, bw[8+ct], acc[ct]);

    POINTWISE(0) POINTWISE(1) POINTWISE(2) POINTWISE(3)

    #pragma unroll
    for (int r=0;r<4;++r){
      hl[w][g4*4+r][l15]    = (_Float16)h0[r];
      hl[w][g4*4+r][l15+16] = (_Float16)h1[r];
    }
    asm volatile("s_waitcnt lgkmcnt(0)" ::: "memory");
    ah = *(const uint4*)&hl[w][l15][g4*8];
  }

  hfragO[(size_t)gw*64 + lane] = ah;
  cO[((size_t)gw*64 + lane)*2]   = make_float4(c0[0],c0[1],c0[2],c0[3]);
  cO[((size_t)gw*64 + lane)*2+1] = make_float4(c1[0],c1[1],c1[2],c1[3]);
  #pragma unroll
  for (int r=0;r<4;++r){
    float p = fmaf(h0[r], fw0, h1[r]*fw1);
    p += __shfl_xor(p, 1, 16); p += __shfl_xor(p, 2, 16);
    p += __shfl_xor(p, 4, 16); p += __shfl_xor(p, 8, 16);
    if (l15 == 0) xn0[r0 + g4*4 + r] = p + fcb[0];
  }
}

// ---------------- fused pred step: (zf + xn*w1) LDS + in-wave gather + cell ----
__global__ __launch_bounds__(256,1)
void k_pred_cell(const float* __restrict__ feat, const float* __restrict__ xnI,
                 const f32x2* __restrict__ zft,
                 const int* __restrict__ ptr, const int2* __restrict__ epack,
                 const float* __restrict__ cw, const float* __restrict__ cb,
                 const uint4* __restrict__ wfrag,
                 const float* __restrict__ fcw, const float* __restrict__ fcb,
                 uint4* __restrict__ hfrag, float4* __restrict__ cS,
                 float* __restrict__ xnO, float* __restrict__ out, int t){
  __shared__ f32x2 zl2[Nn];                   // 32 KB: this batch-slice's z
  __shared__ __align__(16) _Float16 hl[4][16][40];
  int tid = threadIdx.x;
  int lane = tid & 63, w = tid >> 6;
  int gw = blockIdx.x*4 + w;
  int r0 = gw*16;
  int b = r0 >> 12, n0 = r0 & (Nn-1);
  int l15 = lane & 15, g4 = lane >> 4;

  {                                           // stage z = zf + xn*w1row0 (coalesced)
    const f32x2* zsrc = zft + (size_t)b*Nn;
    const float* xb = xnI + (size_t)b*Nn;
    float w10 = cw[20], w11 = cw[21];
    #pragma unroll
    for (int k=0;k<16;++k){
      int idx = tid + k*256;
      f32x2 z = zsrc[idx];
      float xnv = xb[idx];
      zl2[idx] = (f32x2){fmaf(xnv, w10, z.x), fmaf(xnv, w11, z.y)};
    }
  }

  uint4 bw[16];
  #pragma unroll
  for (int f=0; f<16; ++f) bw[f] = wfrag[f*64 + lane];
  float fw0 = fcw[l15], fw1 = fcw[l15+16];

  uint4 ah = hfrag[(size_t)gw*64 + lane];
  float4 cv0 = cS[((size_t)gw*64 + lane)*2];
  float4 cv1 = cS[((size_t)gw*64 + lane)*2+1];
  float c0[4] = {cv0.x, cv0.y, cv0.z, cv0.w};
  float c1[4] = {cv1.x, cv1.y, cv1.z, cv1.w};
  float h0[4], h1[4];
  const f32x4 zacc = {0.f,0.f,0.f,0.f};

  int nrow = n0 + l15;
  const float* fbt = feat + ((size_t)(b*TTC + t)*Nn + n0 + l15)*9;
  float xv[9]; float a0 = 0.f, a1 = 0.f; float x0 = 0.f;
  if (g4 == 0){
    x0 = xnI[r0 + l15];
    #pragma unroll
    for (int f=0;f<7;++f) xv[f] = fbt[f];
    a0 = x0*cw[0]; a1 = x0*cw[1];
    #pragma unroll
    for (int f=0;f<7;++f){ a0 += xv[f]*cw[(f+1)*2]; a1 += xv[f]*cw[(f+1)*2+1]; }
  } else if (g4 == 1){
    xv[7] = fbt[7]; xv[8] = fbt[8];
    a0 = cb[0] + xv[7]*cw[16] + xv[8]*cw[18];
    a1 = cb[1] + xv[7]*cw[17] + xv[8]*cw[19];
  }

  __syncthreads();                            // zl2 ready

  {
    int p0 = ptr[nrow], p1 = ptr[nrow+1];
    for (int i = p0 + g4; i < p1; i += 4){
      int2 e = epack[i];
      float wgt = __int_as_float(e.y);
      f32x2 zv = zl2[e.x];
      a0 = fmaf(wgt, zv.x, a0);
      a1 = fmaf(wgt, zv.y, a1);
    }
    a0 += __shfl_xor(a0, 16); a0 += __shfl_xor(a0, 32);
    a1 += __shfl_xor(a1, 16); a1 += __shfl_xor(a1, 32);
  }
  float xg0 = sigm_f(a0), xg1 = sigm_f(a1);

  uint4 ax;
  if (g4 == 0){
    ax.x = pk2(x0, xv[0]);     ax.y = pk2(xv[1], xv[2]);
    ax.z = pk2(xv[3], xv[4]);  ax.w = pk2(xv[5], xv[6]);
  } else if (g4 == 1){
    ax.x = pk2(xv[7], xv[8]);  ax.y = pk2(xg0, xg1);
    ax.z = pk2(1.f, 0.f);      ax.w = 0u;
  } else {
    ax = make_uint4(0,0,0,0);
  }

  f32x4 acc[8];
  #pragma unroll
  for (int ct=0; ct<8; ++ct) acc[ct] = mfma16(ax, bw[ct], zacc);
  #pragma unroll
  for (int ct=0; ct<8; ++ct) acc[ct] = mfma16(ah, bw[8+ct], acc[ct]);

  POINTWISE(0) POINTWISE(1) POINTWISE(2) POINTWISE(3)

  #pragma unroll
  for (int r=0;r<4;++r){
    hl[w][g4*4+r][l15]    = (_Float16)h0[r];
    hl[w][g4*4+r][l15+16] = (_Float16)h1[r];
  }
  asm volatile("s_waitcnt lgkmcnt(0)" ::: "memory");
  ah = *(const uint4*)&hl[w][l15][g4*8];

  hfrag[(size_t)gw*64 + lane] = ah;
  cS[((size_t)gw*64 + lane)*2]   = make_float4(c0[0],c0[1],c0[2],c0[3]);
  cS[((size_t)gw*64 + lane)*2+1] = make_float4(c1[0],c1[1],c1[2],c1[3]);
  #pragma unroll
  for (int r=0;r<4;++r){
    float p = fmaf(h0[r], fw0, h1[r]*fw1);
    p += __shfl_xor(p, 1, 16); p += __shfl_xor(p, 2, 16);
    p += __shfl_xor(p, 4, 16); p += __shfl_xor(p, 8, 16);
    if (l15 == 0){
      float rr = p + fcb[0];
      int nr = n0 + g4*4 + r;
      xnO[r0 + g4*4 + r] = rr;
      out[(size_t)b*PREDC*Nn + nr] = rr;      // out pre-offset by tp*Nn
    }
  }
}

// ---------------- host ----------------
extern "C" void kernel_launch(void* const* d_in, const int* in_sizes, int n_in,
                              void* d_out, int out_size, void* d_ws, size_t ws_size,
                              hipStream_t stream){
  const float* pm25 = (const float*)d_in[0];
  const float* feat = (const float*)d_in[1];
  const int*   ei   = (const int*)d_in[2];
  const float* cw   = (const float*)d_in[3];
  const float* cb   = (const float*)d_in[4];
  const float* x2hw = (const float*)d_in[5];
  const float* x2hb = (const float*)d_in[6];
  const float* h2hw = (const float*)d_in[7];
  const float* h2hb = (const float*)d_in[8];
  const float* fcw  = (const float*)d_in[9];
  const float* fcb  = (const float*)d_in[10];
  float* out = (float*)d_out;

  char* w = (char*)d_ws;
  size_t off = 0;
  auto take = [&](size_t bytes)->char*{
    char* r = w + off; off += (bytes + 255) & ~(size_t)255; return r;
  };
  int*      deg   = (int*)      take(Nn*4);
  int*      cnt   = (int*)      take(Nn*4);
  int*      fillc = (int*)      take(Nn*4);
  int*      ptr   = (int*)      take((Nn+1)*4);
  float*    dis   = (float*)    take(Nn*4);
  int2*     epack = (int2*)     take(EC*8);
  _Float16* wfrag = (_Float16*) take(16*512*2);
  f32x2*    bufA  = (f32x2*)    take((size_t)HISTC*BN*8);   // zbufH, then aggT
  f32x2*    bufB  = (f32x2*)    take((size_t)HISTC*BN*8);   // zT,   then aggH
  f32x2*    zf    = (f32x2*)    take((size_t)PREDC*BN*8);   // pred feat-z
  uint4*    hfrag = (uint4*)    take((size_t)(BN/16)*64*16);
  float4*   cbuf  = (float4*)   take((size_t)(BN/16)*64*2*16);
  float*    xn0   = (float*)    take((size_t)BN*4);
  float*    xn1   = (float*)    take((size_t)BN*4);

  (void)hipMemsetAsync(deg, 0, Nn*4*3, stream);   // deg,cnt,fillc adjacent

  k_deg <<<EC/256, 256, 0, stream>>>(ei, deg, cnt);
  k_dis <<<Nn/256, 256, 0, stream>>>(deg, dis);
  k_scan<<<1, 1024, 0, stream>>>(cnt, ptr);
  k_fill<<<EC/256, 256, 0, stream>>>(ei, dis, ptr, fillc, epack);
  k_prep<<<32, 256, 0, stream>>>(x2hw, h2hw, x2hb, h2hb, wfrag);

  // hist xg pipeline: z -> zT -> dense agg -> aggH
  k_zh<<<(HISTC*BN)/256, 256, 0, stream>>>(pm25, feat, cw, bufA);
  k_tr<<<512, 256, 0, stream>>>(bufA, bufB, 512, Nn);          // zT[n][512]
  k_agg<<<Nn, 256, 0, stream>>>(ptr, epack, (const float4*)bufB, (float4*)bufA);
  k_tr<<<512, 256, 0, stream>>>(bufA, bufB, Nn, 512);          // aggH[slice][n]

  k_hist<<<BN/64, 256, 0, stream>>>(pm25, feat, bufB, cw, cb,
                                    (const uint4*)wfrag, fcw, fcb,
                                    hfrag, cbuf, xn0);

  k_zf<<<(PREDC*BN)/256, 256, 0, stream>>>(feat, cw, zf);
  for (int tp = 0; tp < PREDC; ++tp){
    int t = HISTC + tp;
    float* xi = (tp & 1) ? xn1 : xn0;
    float* xo = (tp & 1) ? xn0 : xn1;
    k_pred_cell<<<BN/64, 256, 0, stream>>>(feat, xi, zf + (size_t)tp*BN,
                                           ptr, epack, cw, cb,
                                           (const uint4*)wfrag, fcw, fcb,
                                           hfrag, cbuf, xo, out + (size_t)tp*Nn, t);
  }
}